// Round 1
// baseline (2338.904 us; speedup 1.0000x reference)
//
#include <hip/hip_runtime.h>

// ---------------------------------------------------------------------------
// MatchNet: 3-layer MLP (relu after every layer) -> batched PDHG LP solve.
// Shapes: X[2048,64], W1[64,1024], W2[1024,1024], W3[1024,512], S[64,512].
// Output: x [2048,512] fp32.
// ---------------------------------------------------------------------------

typedef _Float16 half8 __attribute__((ext_vector_type(8)));
typedef float floatx4 __attribute__((ext_vector_type(4)));

#define BATCH 2048
#define NCOMBO 64
#define NSTRUCT 512
#define NITERS 60

// ---------------- cast X fp32 -> f16 ----------------
__global__ void cast_x(const float* __restrict__ in, _Float16* __restrict__ out, int n) {
    int i = blockIdx.x * blockDim.x + threadIdx.x;
    if (i < n) out[i] = (_Float16)in[i];
}

// ---------------- transpose + cast W[K][N] fp32 -> Wt[N][K] f16 ----------------
__global__ __launch_bounds__(256) void tcast(const float* __restrict__ W,
                                             _Float16* __restrict__ Wt, int K, int N) {
    __shared__ float tile[32][33];
    int tx = threadIdx.x, ty = threadIdx.y;          // 32 x 8
    int n0 = blockIdx.x * 32, k0 = blockIdx.y * 32;
#pragma unroll
    for (int i = 0; i < 4; i++)
        tile[ty + i * 8][tx] = W[(size_t)(k0 + ty + i * 8) * N + n0 + tx];
    __syncthreads();
#pragma unroll
    for (int i = 0; i < 4; i++)
        Wt[(size_t)(n0 + ty + i * 8) * K + k0 + tx] = (_Float16)tile[tx][ty + i * 8];
}

// ---------------- GEMM: out = relu(A[M,K] @ W[K,N] + bias), A,Wt f16, acc fp32 ----
// Wt is [N][K] (pre-transposed) so both operands are K-contiguous in LDS.
// Block tile 128x64, 256 threads = 4 waves (2x2), wave tile 64x32 via 4x2 MFMA 16x16x32.
__global__ __launch_bounds__(256) void gemm_relu(
    const _Float16* __restrict__ A, const _Float16* __restrict__ Wt,
    const float* __restrict__ bias, _Float16* __restrict__ outh,
    float* __restrict__ outf, int N, int K) {
    __shared__ __align__(16) _Float16 As[128][40];   // +8 pad: breaks 16-bank stride
    __shared__ __align__(16) _Float16 Bs[64][40];
    int tid = threadIdx.x;
    int bm = blockIdx.y * 128;
    int bn = blockIdx.x * 64;
    int w = tid >> 6, l = tid & 63;
    int wr = w >> 1, wc = w & 1;
    int lm = l & 15, q = l >> 4;
    floatx4 acc[4][2] = {};

    int ar = tid >> 1;             // 0..127 (A row)
    int ac = (tid & 1) * 16;       // 0 or 16 (half index within 32-wide K tile)
    int br = tid >> 2;             // 0..63  (B row = n)
    int bc = (tid & 3) * 8;        // 0,8,16,24
    const _Float16* Ag = A + (size_t)(bm + ar) * K;
    const _Float16* Bg = Wt + (size_t)(bn + br) * K;

    for (int k0 = 0; k0 < K; k0 += 32) {
        *(half8*)&As[ar][ac] = *(const half8*)&Ag[k0 + ac];
        *(half8*)&As[ar][ac + 8] = *(const half8*)&Ag[k0 + ac + 8];
        *(half8*)&Bs[br][bc] = *(const half8*)&Bg[k0 + bc];
        __syncthreads();
        half8 af[4], bf[2];
#pragma unroll
        for (int mt = 0; mt < 4; mt++)
            af[mt] = *(const half8*)&As[wr * 64 + mt * 16 + lm][q * 8];
#pragma unroll
        for (int nt = 0; nt < 2; nt++)
            bf[nt] = *(const half8*)&Bs[wc * 32 + nt * 16 + lm][q * 8];
#pragma unroll
        for (int mt = 0; mt < 4; mt++)
#pragma unroll
            for (int nt = 0; nt < 2; nt++)
                acc[mt][nt] = __builtin_amdgcn_mfma_f32_16x16x32_f16(
                    af[mt], bf[nt], acc[mt][nt], 0, 0, 0);
        __syncthreads();
    }
    // epilogue: C/D layout col = lane&15, row = (lane>>4)*4 + reg
#pragma unroll
    for (int nt = 0; nt < 2; nt++) {
        int col = bn + wc * 32 + nt * 16 + lm;
        float bv = bias[col];
#pragma unroll
        for (int mt = 0; mt < 4; mt++) {
#pragma unroll
            for (int v = 0; v < 4; v++) {
                int row = bm + wr * 64 + mt * 16 + q * 4 + v;
                float val = fmaxf(acc[mt][nt][v] + bv, 0.f);
                if (outh) outh[(size_t)row * N + col] = (_Float16)val;
                else      outf[(size_t)row * N + col] = val;
            }
        }
    }
}

// ---------------- build sparse row lists of S + power iteration for tau ----------
__global__ __launch_bounds__(512) void build_power(
    const float* __restrict__ S, int* __restrict__ row_cnt_g,
    unsigned short* __restrict__ row_idx_g, float* __restrict__ tau_g) {
    __shared__ unsigned short rix[64 * 128];
    __shared__ unsigned short cix[512 * 32];
    __shared__ unsigned char cct[512];
    __shared__ int rct[64];
    __shared__ float vv[512], ww[64], red[8];
    __shared__ float nrm_s;
    int t = threadIdx.x;
    if (t < 64) {  // row lists (nonzero column indices of combo row t)
        int c = 0;
        for (int i = 0; i < 512; i++)
            if (S[t * 512 + i] != 0.f) { rix[t * 128 + c] = (unsigned short)i; c++; }
        rct[t] = c;
        row_cnt_g[t] = c;
    }
    {   // column lists (combo rows hitting structure t)
        int c = 0;
        for (int j = 0; j < 64; j++)
            if (S[j * 512 + t] != 0.f) { cix[t * 32 + c] = (unsigned short)j; c++; }
        cct[t] = (unsigned char)c;
    }
    vv[t] = 0.044194173824159216f;  // 1/sqrt(512)
    __syncthreads();
    // persist row lists for pdhg kernel
    for (int qq = 0; qq < 16; qq++) row_idx_g[t * 16 + qq] = rix[t * 16 + qq];
    // 30 normalized power steps on S^T S + I
    for (int s = 0; s < 30; s++) {
        if (t < 64) {
            float a = 0.f;
            for (int qq = 0; qq < rct[t]; qq++) a += vv[rix[t * 128 + qq]];
            ww[t] = a;
        }
        __syncthreads();
        float u = vv[t];
        for (int qq = 0; qq < cct[t]; qq++) u += ww[cix[t * 32 + qq]];
        float n2 = u * u;
#pragma unroll
        for (int o = 32; o > 0; o >>= 1) n2 += __shfl_xor(n2, o, 64);
        if ((t & 63) == 0) red[t >> 6] = n2;
        __syncthreads();
        if (t == 0) {
            float tot = 0.f;
            for (int qq = 0; qq < 8; qq++) tot += red[qq];
            nrm_s = sqrtf(tot);
        }
        __syncthreads();
        float nv = u / nrm_s;
        __syncthreads();
        vv[t] = nv;
        __syncthreads();
    }
    // L = sqrt(v . (S^T S v + v)) with final normalized v
    if (t < 64) {
        float a = 0.f;
        for (int qq = 0; qq < rct[t]; qq++) a += vv[rix[t * 128 + qq]];
        ww[t] = a;
    }
    __syncthreads();
    float u = vv[t];
    for (int qq = 0; qq < cct[t]; qq++) u += ww[cix[t * 32 + qq]];
    float n2 = vv[t] * u;
#pragma unroll
    for (int o = 32; o > 0; o >>= 1) n2 += __shfl_xor(n2, o, 64);
    if ((t & 63) == 0) red[t >> 6] = n2;
    __syncthreads();
    if (t == 0) {
        float tot = 0.f;
        for (int qq = 0; qq < 8; qq++) tot += red[qq];
        tau_g[0] = 0.9f / sqrtf(tot);
    }
}

// ---------------- fused 60-iteration PDHG, one wave per batch row ----------------
// y_lo gather uses row lists of S (Kx = S.xbar); KTy uses the SAME lists as a
// scatter (LDS atomicAdd) from the lane owning y_lo[j] -- no column lists needed.
__global__ __launch_bounds__(64) void pdhg_kernel(
    const float* __restrict__ Z, const float* __restrict__ Xf,
    const int* __restrict__ row_cnt, const unsigned short* __restrict__ row_idx,
    const float* __restrict__ tau_p, float* __restrict__ out) {
    __shared__ float xbar_s[516];
    __shared__ float kty_s[516];
    int l = threadIdx.x;
    int b = blockIdx.x;
    float tau = tau_p[0];
    float sig = tau;
    float z[8], x[8], xb[8], yhi[8];
#pragma unroll
    for (int k = 0; k < 8; k++) {
        z[k] = Z[(size_t)b * 512 + k * 64 + l];
        x[k] = 0.f; xb[k] = 0.f; yhi[k] = 0.f;
        xbar_s[k * 64 + l] = 0.f;
        kty_s[k * 64 + l] = 0.f;
    }
    float Bcap = Xf[(size_t)b * 64 + l];
    float ylo = 0.f;
    int rc = row_cnt[l];
    const unsigned short* rlist = row_idx + l * 128;
    __syncthreads();
    for (int it = 0; it < NITERS; ++it) {
        // kx_l = (S xbar)_l  : gather over row-l nonzeros
        float kx = 0.f;
        for (int t = 0; t < rc; ++t) kx += xbar_s[rlist[t]];
        ylo = fmaxf(ylo + sig * (kx - Bcap), 0.f);
#pragma unroll
        for (int k = 0; k < 8; k++) yhi[k] = fmaxf(yhi[k] - sig * xb[k], 0.f);
        // scatter: kty_s[i] += ylo for i in row l   (S^T y_lo)
        for (int t = 0; t < rc; ++t) atomicAdd(&kty_s[rlist[t]], ylo);
        __syncthreads();   // scatter done; all xbar_s reads done
        float d[8];
        float nrm2 = 0.f;
#pragma unroll
        for (int k = 0; k < 8; k++) {
            float kty = kty_s[k * 64 + l] - yhi[k];
            float v = x[k] - tau * kty;
            float u = v + tau;           // + tau * W, W = 1
            d[k] = u - z[k];
            nrm2 += d[k] * d[k];
        }
#pragma unroll
        for (int o = 32; o > 0; o >>= 1) nrm2 += __shfl_xor(nrm2, o, 64);
        float nrm = sqrtf(nrm2);
        float scale = fmaxf(1.f - tau / fmaxf(nrm, 1e-12f), 0.f);
#pragma unroll
        for (int k = 0; k < 8; k++) {
            float xn = z[k] + scale * d[k];
            xb[k] = 2.f * xn - x[k];
            x[k] = xn;
            xbar_s[k * 64 + l] = xb[k];
            kty_s[k * 64 + l] = 0.f;
        }
        __syncthreads();   // new xbar / zeroed kty visible before next iter
    }
#pragma unroll
    for (int k = 0; k < 8; k++) out[(size_t)b * 512 + k * 64 + l] = x[k];
}

// ---------------------------------------------------------------------------
extern "C" void kernel_launch(void* const* d_in, const int* in_sizes, int n_in,
                              void* d_out, int out_size, void* d_ws, size_t ws_size,
                              hipStream_t stream) {
    const float* X  = (const float*)d_in[0];
    const float* W1 = (const float*)d_in[1];
    const float* b1 = (const float*)d_in[2];
    const float* W2 = (const float*)d_in[3];
    const float* b2 = (const float*)d_in[4];
    const float* W3 = (const float*)d_in[5];
    const float* b3 = (const float*)d_in[6];
    const float* S  = (const float*)d_in[7];
    float* out = (float*)d_out;

    char* ws = (char*)d_ws;
    size_t off = 0;
    auto alloc = [&](size_t bytes) {
        void* p = ws + off;
        off += (bytes + 255) & ~(size_t)255;
        return p;
    };
    _Float16* Xh  = (_Float16*)alloc((size_t)BATCH * 64 * 2);
    _Float16* W1t = (_Float16*)alloc((size_t)64 * 1024 * 2);
    _Float16* W2t = (_Float16*)alloc((size_t)1024 * 1024 * 2);
    _Float16* W3t = (_Float16*)alloc((size_t)1024 * 512 * 2);
    _Float16* H1  = (_Float16*)alloc((size_t)BATCH * 1024 * 2);
    _Float16* H2  = (_Float16*)alloc((size_t)BATCH * 1024 * 2);
    float*    Zb  = (float*)alloc((size_t)BATCH * 512 * 4);
    int*      row_cnt = (int*)alloc(64 * 4);
    unsigned short* row_idx = (unsigned short*)alloc(64 * 128 * 2);
    float*    tau = (float*)alloc(256);

    hipLaunchKernelGGL(cast_x, dim3(512), dim3(256), 0, stream, X, Xh, BATCH * 64);
    hipLaunchKernelGGL(tcast, dim3(32, 2),  dim3(32, 8), 0, stream, W1, W1t, 64, 1024);
    hipLaunchKernelGGL(tcast, dim3(32, 32), dim3(32, 8), 0, stream, W2, W2t, 1024, 1024);
    hipLaunchKernelGGL(tcast, dim3(16, 32), dim3(32, 8), 0, stream, W3, W3t, 1024, 512);
    hipLaunchKernelGGL(build_power, dim3(1), dim3(512), 0, stream, S, row_cnt, row_idx, tau);
    hipLaunchKernelGGL(gemm_relu, dim3(16, 16), dim3(256), 0, stream,
                       Xh, W1t, b1, H1, (float*)nullptr, 1024, 64);
    hipLaunchKernelGGL(gemm_relu, dim3(16, 16), dim3(256), 0, stream,
                       H1, W2t, b2, H2, (float*)nullptr, 1024, 1024);
    hipLaunchKernelGGL(gemm_relu, dim3(8, 16), dim3(256), 0, stream,
                       H2, W3t, b3, (_Float16*)nullptr, Zb, 512, 1024);
    hipLaunchKernelGGL(pdhg_kernel, dim3(BATCH), dim3(64), 0, stream,
                       Zb, X, row_cnt, row_idx, tau, out);
}

// Round 2
// 2320.818 us; speedup vs baseline: 1.0078x; 1.0078x over previous
//
#include <hip/hip_runtime.h>

// ---------------------------------------------------------------------------
// MatchNet: 3-layer MLP (relu after every layer) -> batched PDHG LP solve.
// Shapes: X[2048,64], W1[64,1024], W2[1024,1024], W3[1024,512], S[64,512].
// Output: x [2048,512] fp32.
// ---------------------------------------------------------------------------

typedef _Float16 half8 __attribute__((ext_vector_type(8)));
typedef float floatx4 __attribute__((ext_vector_type(4)));

#define BATCH 2048
#define NCOMBO 64
#define NSTRUCT 512
#define NITERS 60
#define RCAP 96    // max nnz per S-row (mean ~41, sigma ~6: 9-sigma headroom)
#define RCAPW 48   // packed uint pairs per row

// ---------------- cast X fp32 -> f16 ----------------
__global__ void cast_x(const float* __restrict__ in, _Float16* __restrict__ out, int n) {
    int i = blockIdx.x * blockDim.x + threadIdx.x;
    if (i < n) out[i] = (_Float16)in[i];
}

// ---------------- transpose + cast W[K][N] fp32 -> Wt[N][K] f16 ----------------
__global__ __launch_bounds__(256) void tcast(const float* __restrict__ W,
                                             _Float16* __restrict__ Wt, int K, int N) {
    __shared__ float tile[32][33];
    int tx = threadIdx.x, ty = threadIdx.y;          // 32 x 8
    int n0 = blockIdx.x * 32, k0 = blockIdx.y * 32;
#pragma unroll
    for (int i = 0; i < 4; i++)
        tile[ty + i * 8][tx] = W[(size_t)(k0 + ty + i * 8) * N + n0 + tx];
    __syncthreads();
#pragma unroll
    for (int i = 0; i < 4; i++)
        Wt[(size_t)(n0 + ty + i * 8) * K + k0 + tx] = (_Float16)tile[tx][ty + i * 8];
}

// ---------------- GEMM: out = relu(A[M,K] @ W[K,N] + bias), A,Wt f16, acc fp32 ----
__global__ __launch_bounds__(256) void gemm_relu(
    const _Float16* __restrict__ A, const _Float16* __restrict__ Wt,
    const float* __restrict__ bias, _Float16* __restrict__ outh,
    float* __restrict__ outf, int N, int K) {
    __shared__ __align__(16) _Float16 As[128][40];
    __shared__ __align__(16) _Float16 Bs[64][40];
    int tid = threadIdx.x;
    int bm = blockIdx.y * 128;
    int bn = blockIdx.x * 64;
    int w = tid >> 6, l = tid & 63;
    int wr = w >> 1, wc = w & 1;
    int lm = l & 15, q = l >> 4;
    floatx4 acc[4][2] = {};

    int ar = tid >> 1;
    int ac = (tid & 1) * 16;
    int br = tid >> 2;
    int bc = (tid & 3) * 8;
    const _Float16* Ag = A + (size_t)(bm + ar) * K;
    const _Float16* Bg = Wt + (size_t)(bn + br) * K;

    for (int k0 = 0; k0 < K; k0 += 32) {
        *(half8*)&As[ar][ac] = *(const half8*)&Ag[k0 + ac];
        *(half8*)&As[ar][ac + 8] = *(const half8*)&Ag[k0 + ac + 8];
        *(half8*)&Bs[br][bc] = *(const half8*)&Bg[k0 + bc];
        __syncthreads();
        half8 af[4], bf[2];
#pragma unroll
        for (int mt = 0; mt < 4; mt++)
            af[mt] = *(const half8*)&As[wr * 64 + mt * 16 + lm][q * 8];
#pragma unroll
        for (int nt = 0; nt < 2; nt++)
            bf[nt] = *(const half8*)&Bs[wc * 32 + nt * 16 + lm][q * 8];
#pragma unroll
        for (int mt = 0; mt < 4; mt++)
#pragma unroll
            for (int nt = 0; nt < 2; nt++)
                acc[mt][nt] = __builtin_amdgcn_mfma_f32_16x16x32_f16(
                    af[mt], bf[nt], acc[mt][nt], 0, 0, 0);
        __syncthreads();
    }
#pragma unroll
    for (int nt = 0; nt < 2; nt++) {
        int col = bn + wc * 32 + nt * 16 + lm;
        float bv = bias[col];
#pragma unroll
        for (int mt = 0; mt < 4; mt++) {
#pragma unroll
            for (int v = 0; v < 4; v++) {
                int row = bm + wr * 64 + mt * 16 + q * 4 + v;
                float val = fmaxf(acc[mt][nt][v] + bv, 0.f);
                if (outh) outh[(size_t)row * N + col] = (_Float16)val;
                else      outf[(size_t)row * N + col] = val;
            }
        }
    }
}

// ---------------- sparse lists of S + power iteration for tau ----------
// Row lists built by ballot-compaction (8 waves x 8 rows x 8 chunks of 64 cols),
// then rotated per-row by (row*nnz)/64 so that in pdhg, at gather step p the 64
// lanes hit decorrelated LDS banks (sorted lists otherwise cluster addresses).
__global__ __launch_bounds__(512) void build_power(
    const float* __restrict__ S, int* __restrict__ row_cnt_g,
    unsigned int* __restrict__ row_pairs_g, float* __restrict__ tau_g) {
    __shared__ unsigned short rix[64 * RCAP];    // compacted (sorted) row lists
    __shared__ unsigned short rrot[64 * RCAP];   // rotated + padded
    __shared__ unsigned short cix[512 * 32];
    __shared__ unsigned char cct[512];
    __shared__ int rct[64];
    __shared__ float vv[512], ww[64], red[8];
    __shared__ float nrm_s;
    int t = threadIdx.x;
    int wv = t >> 6, ln = t & 63;

    // row lists via ballot compaction: wave wv handles rows wv*8 .. wv*8+7
    for (int rr = 0; rr < 8; ++rr) {
        int r = wv * 8 + rr;
        int base = 0;
        for (int c = 0; c < 8; ++c) {
            float v = S[r * 512 + c * 64 + ln];
            unsigned long long m = __ballot(v != 0.f);
            if (v != 0.f) {
                int pos = __popcll(m & ((1ull << ln) - 1ull));
                rix[r * RCAP + base + pos] = (unsigned short)(c * 64 + ln);
            }
            base += __popcll(m);
        }
        if (ln == 0) { rct[r] = base; row_cnt_g[r] = base; }
    }
    // column lists: thread t scans column t over 64 rows (for power iter only)
    {
        int c = 0;
        for (int j = 0; j < 64; j++)
            if (S[j * 512 + t] != 0.f) { cix[t * 32 + c] = (unsigned short)j; c++; }
        cct[t] = (unsigned char)c;
    }
    vv[t] = 0.044194173824159216f;  // 1/sqrt(512)
    __syncthreads();

    // rotate + pack row lists (threads 0..63, one row each)
    if (t < 64) {
        int rc = rct[t];
        int rot = (t * rc) >> 6;
        for (int j = 0; j < rc; ++j) {
            int pos = j + rot; if (pos >= rc) pos -= rc;
            rrot[t * RCAP + pos] = rix[t * RCAP + j];
        }
        if (rc & 1) rrot[t * RCAP + rc] = (unsigned short)(512 + (t & 15));  // dummy
        int pc = (rc + 1) >> 1;
        for (int p = 0; p < pc; ++p) {
            unsigned int lo = rrot[t * RCAP + 2 * p];
            unsigned int hi = rrot[t * RCAP + 2 * p + 1];
            row_pairs_g[t * RCAPW + p] = lo | (hi << 16);
        }
    }
    __syncthreads();

    // 30 normalized power steps on S^T S + I
    for (int s = 0; s < 30; s++) {
        if (t < 64) {
            float a = 0.f;
            for (int qq = 0; qq < rct[t]; qq++) a += vv[rix[t * RCAP + qq]];
            ww[t] = a;
        }
        __syncthreads();
        float u = vv[t];
        for (int qq = 0; qq < cct[t]; qq++) u += ww[cix[t * 32 + qq]];
        float n2 = u * u;
#pragma unroll
        for (int o = 32; o > 0; o >>= 1) n2 += __shfl_xor(n2, o, 64);
        if ((t & 63) == 0) red[t >> 6] = n2;
        __syncthreads();
        if (t == 0) {
            float tot = 0.f;
            for (int qq = 0; qq < 8; qq++) tot += red[qq];
            nrm_s = sqrtf(tot);
        }
        __syncthreads();
        float nv = u / nrm_s;
        __syncthreads();
        vv[t] = nv;
        __syncthreads();
    }
    // L = sqrt(v . (S^T S v + v)) with final normalized v
    if (t < 64) {
        float a = 0.f;
        for (int qq = 0; qq < rct[t]; qq++) a += vv[rix[t * RCAP + qq]];
        ww[t] = a;
    }
    __syncthreads();
    float u = vv[t];
    for (int qq = 0; qq < cct[t]; qq++) u += ww[cix[t * 32 + qq]];
    float n2 = vv[t] * u;
#pragma unroll
    for (int o = 32; o > 0; o >>= 1) n2 += __shfl_xor(n2, o, 64);
    if ((t & 63) == 0) red[t >> 6] = n2;
    __syncthreads();
    if (t == 0) {
        float tot = 0.f;
        for (int qq = 0; qq < 8; qq++) tot += red[qq];
        tau_g[0] = 0.9f / sqrtf(tot);
    }
}

// ---------------- fused 60-iteration PDHG, one wave per batch row ----------------
// All iteration-loop traffic is LDS/registers: lists preloaded to LDS (packed
// index pairs, exact per-lane counts), gather = S.xbar via row list, scatter =
// S^T.y_lo via LDS atomicAdd on the SAME list. Odd-count pad entry targets the
// dummy slots [512..527] (xbar dummy reads 0; kty dummy adds are never read).
__global__ __launch_bounds__(64) void pdhg_kernel(
    const float* __restrict__ Z, const float* __restrict__ Xf,
    const int* __restrict__ row_cnt, const unsigned int* __restrict__ row_pairs,
    const float* __restrict__ tau_p, float* __restrict__ out) {
    __shared__ float xbar_s[528];
    __shared__ float kty_s[528];
    __shared__ unsigned int rl_s[64 * RCAPW];
    int l = threadIdx.x;
    int b = blockIdx.x;
    // preload lists: 3072 uints, coalesced, L2-hot (same for every block)
    for (int i = l; i < 64 * RCAPW; i += 64) rl_s[i] = row_pairs[i];
    float tau = tau_p[0];
    float sig = tau;
    float z[8], x[8], xb[8], yhi[8];
#pragma unroll
    for (int k = 0; k < 8; k++) {
        z[k] = Z[(size_t)b * 512 + k * 64 + l];
        x[k] = 0.f; xb[k] = 0.f; yhi[k] = 0.f;
        xbar_s[k * 64 + l] = 0.f;
        kty_s[k * 64 + l] = 0.f;
    }
    if (l < 16) { xbar_s[512 + l] = 0.f; kty_s[512 + l] = 0.f; }
    float Bcap = Xf[(size_t)b * 64 + l];
    float ylo = 0.f;
    int pc = (row_cnt[l] + 1) >> 1;   // packed-pair count for this lane's row
    const unsigned int* rl = &rl_s[l * RCAPW];
    __syncthreads();
    for (int it = 0; it < NITERS; ++it) {
        // kx_l = (S xbar)_l : gather, 2 indices per packed uint
        float kx = 0.f;
        for (int p = 0; p < pc; ++p) {
            unsigned int pr = rl[p];
            kx += xbar_s[pr & 0xffffu];
            kx += xbar_s[pr >> 16];
        }
        ylo = fmaxf(ylo + sig * (kx - Bcap), 0.f);
#pragma unroll
        for (int k = 0; k < 8; k++) yhi[k] = fmaxf(yhi[k] - sig * xb[k], 0.f);
        // kty_s[i] += ylo for i in row l  (S^T y_lo)
        for (int p = 0; p < pc; ++p) {
            unsigned int pr = rl[p];
            atomicAdd(&kty_s[pr & 0xffffu], ylo);
            atomicAdd(&kty_s[pr >> 16], ylo);
        }
        __syncthreads();   // scatter done; all xbar_s reads done
        float d[8];
        float nrm2 = 0.f;
#pragma unroll
        for (int k = 0; k < 8; k++) {
            float kty = kty_s[k * 64 + l] - yhi[k];
            float v = x[k] - tau * kty;
            float u = v + tau;           // + tau * W, W = 1
            d[k] = u - z[k];
            nrm2 += d[k] * d[k];
        }
#pragma unroll
        for (int o = 32; o > 0; o >>= 1) nrm2 += __shfl_xor(nrm2, o, 64);
        float nrm = sqrtf(nrm2);
        float scale = fmaxf(1.f - tau / fmaxf(nrm, 1e-12f), 0.f);
#pragma unroll
        for (int k = 0; k < 8; k++) {
            float xn = z[k] + scale * d[k];
            xb[k] = 2.f * xn - x[k];
            x[k] = xn;
            xbar_s[k * 64 + l] = xb[k];
            kty_s[k * 64 + l] = 0.f;
        }
        __syncthreads();   // new xbar / zeroed kty visible before next iter
    }
#pragma unroll
    for (int k = 0; k < 8; k++) out[(size_t)b * 512 + k * 64 + l] = x[k];
}

// ---------------------------------------------------------------------------
extern "C" void kernel_launch(void* const* d_in, const int* in_sizes, int n_in,
                              void* d_out, int out_size, void* d_ws, size_t ws_size,
                              hipStream_t stream) {
    const float* X  = (const float*)d_in[0];
    const float* W1 = (const float*)d_in[1];
    const float* b1 = (const float*)d_in[2];
    const float* W2 = (const float*)d_in[3];
    const float* b2 = (const float*)d_in[4];
    const float* W3 = (const float*)d_in[5];
    const float* b3 = (const float*)d_in[6];
    const float* S  = (const float*)d_in[7];
    float* out = (float*)d_out;

    char* ws = (char*)d_ws;
    size_t off = 0;
    auto alloc = [&](size_t bytes) {
        void* p = ws + off;
        off += (bytes + 255) & ~(size_t)255;
        return p;
    };
    _Float16* Xh  = (_Float16*)alloc((size_t)BATCH * 64 * 2);
    _Float16* W1t = (_Float16*)alloc((size_t)64 * 1024 * 2);
    _Float16* W2t = (_Float16*)alloc((size_t)1024 * 1024 * 2);
    _Float16* W3t = (_Float16*)alloc((size_t)1024 * 512 * 2);
    _Float16* H1  = (_Float16*)alloc((size_t)BATCH * 1024 * 2);
    _Float16* H2  = (_Float16*)alloc((size_t)BATCH * 1024 * 2);
    float*    Zb  = (float*)alloc((size_t)BATCH * 512 * 4);
    int*      row_cnt = (int*)alloc(64 * 4);
    unsigned int* row_pairs = (unsigned int*)alloc(64 * RCAPW * 4);
    float*    tau = (float*)alloc(256);

    hipLaunchKernelGGL(cast_x, dim3(512), dim3(256), 0, stream, X, Xh, BATCH * 64);
    hipLaunchKernelGGL(tcast, dim3(32, 2),  dim3(32, 8), 0, stream, W1, W1t, 64, 1024);
    hipLaunchKernelGGL(tcast, dim3(32, 32), dim3(32, 8), 0, stream, W2, W2t, 1024, 1024);
    hipLaunchKernelGGL(tcast, dim3(16, 32), dim3(32, 8), 0, stream, W3, W3t, 1024, 512);
    hipLaunchKernelGGL(build_power, dim3(1), dim3(512), 0, stream, S, row_cnt, row_pairs, tau);
    hipLaunchKernelGGL(gemm_relu, dim3(16, 16), dim3(256), 0, stream,
                       Xh, W1t, b1, H1, (float*)nullptr, 1024, 64);
    hipLaunchKernelGGL(gemm_relu, dim3(16, 16), dim3(256), 0, stream,
                       H1, W2t, b2, H2, (float*)nullptr, 1024, 1024);
    hipLaunchKernelGGL(gemm_relu, dim3(8, 16), dim3(256), 0, stream,
                       H2, W3t, b3, (_Float16*)nullptr, Zb, 512, 1024);
    hipLaunchKernelGGL(pdhg_kernel, dim3(BATCH), dim3(64), 0, stream,
                       Zb, X, row_cnt, row_pairs, tau, out);
}

// Round 3
// 453.984 us; speedup vs baseline: 5.1520x; 5.1121x over previous
//
#include <hip/hip_runtime.h>

// ---------------------------------------------------------------------------
// MatchNet: 3-layer MLP (relu after every layer) -> batched PDHG LP solve.
// Shapes: X[2048,64], W1[64,1024], W2[1024,1024], W3[1024,512], S[64,512].
// Output: x [2048,512] fp32.
//
// R3: PDHG restructured from LDS gather/scatter (latency-chain-bound, 2.09 ms)
// to dense MFMA: S is 0/1 (exact in f16); Kx and KTy are 16x64x512 / 16x512x64
// f16 GEMMs per 16-row tile, with hi/lo f16 splitting of xbar / y_lo for
// fp32-level accuracy. S fragments live in VGPRs (constant across iters).
// ---------------------------------------------------------------------------

typedef _Float16 half8 __attribute__((ext_vector_type(8)));
typedef float floatx4 __attribute__((ext_vector_type(4)));

#define BATCH 2048
#define NITERS 60
#define RCAP 96
#define XBS 520   // xbar LDS row stride (halves); dword stride 260 % 32 == 4 -> uniform banks
#define YLS 72    // ylo  LDS row stride (halves)

// ---------------- cast X fp32 -> f16 ----------------
__global__ void cast_x(const float* __restrict__ in, _Float16* __restrict__ out, int n) {
    int i = blockIdx.x * blockDim.x + threadIdx.x;
    if (i < n) out[i] = (_Float16)in[i];
}

// ---------------- transpose + cast W[K][N] fp32 -> Wt[N][K] f16 ----------------
__global__ __launch_bounds__(256) void tcast(const float* __restrict__ W,
                                             _Float16* __restrict__ Wt, int K, int N) {
    __shared__ float tile[32][33];
    int tx = threadIdx.x, ty = threadIdx.y;          // 32 x 8
    int n0 = blockIdx.x * 32, k0 = blockIdx.y * 32;
#pragma unroll
    for (int i = 0; i < 4; i++)
        tile[ty + i * 8][tx] = W[(size_t)(k0 + ty + i * 8) * N + n0 + tx];
    __syncthreads();
#pragma unroll
    for (int i = 0; i < 4; i++)
        Wt[(size_t)(n0 + ty + i * 8) * K + k0 + tx] = (_Float16)tile[tx][ty + i * 8];
}

// ---------------- GEMM: out = relu(A[M,K] @ W[K,N] + bias), A,Wt f16, acc fp32 ----
__global__ __launch_bounds__(256) void gemm_relu(
    const _Float16* __restrict__ A, const _Float16* __restrict__ Wt,
    const float* __restrict__ bias, _Float16* __restrict__ outh,
    float* __restrict__ outf, int N, int K) {
    __shared__ __align__(16) _Float16 As[128][40];
    __shared__ __align__(16) _Float16 Bs[64][40];
    int tid = threadIdx.x;
    int bm = blockIdx.y * 128;
    int bn = blockIdx.x * 64;
    int w = tid >> 6, l = tid & 63;
    int wr = w >> 1, wc = w & 1;
    int lm = l & 15, q = l >> 4;
    floatx4 acc[4][2] = {};

    int ar = tid >> 1;
    int ac = (tid & 1) * 16;
    int br = tid >> 2;
    int bc = (tid & 3) * 8;
    const _Float16* Ag = A + (size_t)(bm + ar) * K;
    const _Float16* Bg = Wt + (size_t)(bn + br) * K;

    for (int k0 = 0; k0 < K; k0 += 32) {
        *(half8*)&As[ar][ac] = *(const half8*)&Ag[k0 + ac];
        *(half8*)&As[ar][ac + 8] = *(const half8*)&Ag[k0 + ac + 8];
        *(half8*)&Bs[br][bc] = *(const half8*)&Bg[k0 + bc];
        __syncthreads();
        half8 af[4], bf[2];
#pragma unroll
        for (int mt = 0; mt < 4; mt++)
            af[mt] = *(const half8*)&As[wr * 64 + mt * 16 + lm][q * 8];
#pragma unroll
        for (int nt = 0; nt < 2; nt++)
            bf[nt] = *(const half8*)&Bs[wc * 32 + nt * 16 + lm][q * 8];
#pragma unroll
        for (int mt = 0; mt < 4; mt++)
#pragma unroll
            for (int nt = 0; nt < 2; nt++)
                acc[mt][nt] = __builtin_amdgcn_mfma_f32_16x16x32_f16(
                    af[mt], bf[nt], acc[mt][nt], 0, 0, 0);
        __syncthreads();
    }
#pragma unroll
    for (int nt = 0; nt < 2; nt++) {
        int col = bn + wc * 32 + nt * 16 + lm;
        float bv = bias[col];
#pragma unroll
        for (int mt = 0; mt < 4; mt++) {
#pragma unroll
            for (int v = 0; v < 4; v++) {
                int row = bm + wr * 64 + mt * 16 + q * 4 + v;
                float val = fmaxf(acc[mt][nt][v] + bv, 0.f);
                if (outh) outh[(size_t)row * N + col] = (_Float16)val;
                else      outf[(size_t)row * N + col] = val;
            }
        }
    }
}

// ---------------- power iteration for tau + S MFMA-fragment build --------------
// Fragment layouts (16x16x32 f16, verified by the passing gemm_relu):
//  s1f: B-frag of S^T for Kx.  i = ((wc*16+kk)*64 + lane)*8 + j
//       value = S[wc*16 + (lane&15)][kk*32 + (lane>>4)*8 + j]
//  s2f: B-frag of S for KTy.   i = (((wc*8+t)*2+c)*64 + lane)*8 + j
//       value = S[c*32 + (lane>>4)*8 + j][wc*128 + t*16 + (lane&15)]
__global__ __launch_bounds__(512) void build_power(
    const float* __restrict__ S, _Float16* __restrict__ s1f,
    _Float16* __restrict__ s2f, float* __restrict__ tau_g) {
    __shared__ unsigned short rix[64 * RCAP];
    __shared__ unsigned short cix[512 * 32];
    __shared__ unsigned char cct[512];
    __shared__ int rct[64];
    __shared__ float vv[512], ww[64], red[8];
    __shared__ float nrm_s;
    int t = threadIdx.x;
    int wv = t >> 6, ln = t & 63;

    // MFMA fragments of S (constant data, consumed from VGPRs in pdhg_mfma)
    for (int i = t; i < 4 * 16 * 64 * 8; i += 512) {
        int j = i & 7, lane = (i >> 3) & 63, kk = (i >> 9) & 15, wc = i >> 13;
        int m = wc * 16 + (lane & 15);
        int k = kk * 32 + (lane >> 4) * 8 + j;
        s1f[i] = (_Float16)S[m * 512 + k];
    }
    for (int i = t; i < 4 * 8 * 2 * 64 * 8; i += 512) {
        int j = i & 7, lane = (i >> 3) & 63, c = (i >> 9) & 1, tt = (i >> 10) & 7, wc = i >> 13;
        int kc = c * 32 + (lane >> 4) * 8 + j;
        int n = wc * 128 + tt * 16 + (lane & 15);
        s2f[i] = (_Float16)S[kc * 512 + n];
    }

    // sparse lists for the power iteration
    for (int rr = 0; rr < 8; ++rr) {
        int r = wv * 8 + rr;
        int base = 0;
        for (int c = 0; c < 8; ++c) {
            float v = S[r * 512 + c * 64 + ln];
            unsigned long long m = __ballot(v != 0.f);
            if (v != 0.f) {
                int pos = __popcll(m & ((1ull << ln) - 1ull));
                rix[r * RCAP + base + pos] = (unsigned short)(c * 64 + ln);
            }
            base += __popcll(m);
        }
        if (ln == 0) rct[r] = base;
    }
    {
        int c = 0;
        for (int j = 0; j < 64; j++)
            if (S[j * 512 + t] != 0.f) { cix[t * 32 + c] = (unsigned short)j; c++; }
        cct[t] = (unsigned char)c;
    }
    vv[t] = 0.044194173824159216f;  // 1/sqrt(512)
    __syncthreads();

    // 30 normalized power steps on S^T S + I
    for (int s = 0; s < 30; s++) {
        if (t < 64) {
            float a = 0.f;
            for (int qq = 0; qq < rct[t]; qq++) a += vv[rix[t * RCAP + qq]];
            ww[t] = a;
        }
        __syncthreads();
        float u = vv[t];
        for (int qq = 0; qq < cct[t]; qq++) u += ww[cix[t * 32 + qq]];
        float n2 = u * u;
#pragma unroll
        for (int o = 32; o > 0; o >>= 1) n2 += __shfl_xor(n2, o, 64);
        if ((t & 63) == 0) red[t >> 6] = n2;
        __syncthreads();
        if (t == 0) {
            float tot = 0.f;
            for (int qq = 0; qq < 8; qq++) tot += red[qq];
            nrm_s = sqrtf(tot);
        }
        __syncthreads();
        float nv = u / nrm_s;
        __syncthreads();
        vv[t] = nv;
        __syncthreads();
    }
    if (t < 64) {
        float a = 0.f;
        for (int qq = 0; qq < rct[t]; qq++) a += vv[rix[t * RCAP + qq]];
        ww[t] = a;
    }
    __syncthreads();
    float u = vv[t];
    for (int qq = 0; qq < cct[t]; qq++) u += ww[cix[t * 32 + qq]];
    float n2 = vv[t] * u;
#pragma unroll
    for (int o = 32; o > 0; o >>= 1) n2 += __shfl_xor(n2, o, 64);
    if ((t & 63) == 0) red[t >> 6] = n2;
    __syncthreads();
    if (t == 0) {
        float tot = 0.f;
        for (int qq = 0; qq < 8; qq++) tot += red[qq];
        tau_g[0] = 0.9f / sqrtf(tot);
    }
}

// ---------------- MFMA-dense 60-iteration PDHG ---------------------------------
// Workgroup = 16 batch rows, 4 waves; wave wc owns combos [wc*16,wc*16+16) and
// struct cols [wc*128, wc*128+128). All state in registers, C/D layout
// (row = q*4+v, col = ...+lm). xbar / y_lo cross wave boundaries -> LDS round
// trip as f16 hi+lo planes (split gives fp32-level accuracy; S side is exact).
__global__ __launch_bounds__(256, 1) void pdhg_mfma(
    const float* __restrict__ Zb, const float* __restrict__ Xf,
    const _Float16* __restrict__ s1f, const _Float16* __restrict__ s2f,
    const float* __restrict__ tau_p, float* __restrict__ out) {
    __shared__ __align__(16) _Float16 xb_hi[16 * XBS];
    __shared__ __align__(16) _Float16 xb_lo[16 * XBS];
    __shared__ __align__(16) _Float16 yl_hi[16 * YLS];
    __shared__ __align__(16) _Float16 yl_lo[16 * YLS];
    __shared__ __align__(16) float red[16][4];
    int tid = threadIdx.x;
    int wc = tid >> 6, l = tid & 63, lm = l & 15, q = l >> 4;
    int b0 = blockIdx.x * 16;

    // constant S fragments -> registers (held across all 60 iterations)
    half8 s1[16], s2[8][2];
#pragma unroll
    for (int kk = 0; kk < 16; kk++)
        s1[kk] = *(const half8*)&s1f[((wc * 16 + kk) * 64 + l) * 8];
#pragma unroll
    for (int t = 0; t < 8; t++)
#pragma unroll
        for (int c = 0; c < 2; c++)
            s2[t][c] = *(const half8*)&s2f[(((wc * 8 + t) * 2 + c) * 64 + l) * 8];

    float z[4][8], x[4][8], xb[4][8], yhi[4][8];
    floatx4 ylo, Bc;
#pragma unroll
    for (int v = 0; v < 4; v++) {
        int row = b0 + q * 4 + v;
        Bc[v] = Xf[row * 64 + wc * 16 + lm];
        ylo[v] = 0.f;
#pragma unroll
        for (int t = 0; t < 8; t++) {
            z[v][t] = Zb[(size_t)row * 512 + wc * 128 + t * 16 + lm];
            x[v][t] = 0.f; xb[v][t] = 0.f; yhi[v][t] = 0.f;
        }
    }
    // zero xbar planes (8320 halves each; 1040 half8 stores per plane)
    {
        half8 hz = {0, 0, 0, 0, 0, 0, 0, 0};
        for (int i = tid; i < (16 * XBS) / 8; i += 256) {
            *(half8*)&xb_hi[i * 8] = hz;
            *(half8*)&xb_lo[i * 8] = hz;
        }
    }
    float tau = tau_p[0];
    float sig = tau;
    __syncthreads();

#pragma unroll 1
    for (int it = 0; it < NITERS; ++it) {
        // ---- Kx tile: a1[16 rows x 16 combos] = Xbar @ S^T (hi+lo split) ----
        floatx4 a1 = {0.f, 0.f, 0.f, 0.f};
#pragma unroll
        for (int kk = 0; kk < 16; kk++) {
            half8 ah = *(const half8*)&xb_hi[lm * XBS + kk * 32 + q * 8];
            half8 al = *(const half8*)&xb_lo[lm * XBS + kk * 32 + q * 8];
            a1 = __builtin_amdgcn_mfma_f32_16x16x32_f16(ah, s1[kk], a1, 0, 0, 0);
            a1 = __builtin_amdgcn_mfma_f32_16x16x32_f16(al, s1[kk], a1, 0, 0, 0);
        }
        // ---- y_lo update + publish hi/lo planes ----
#pragma unroll
        for (int v = 0; v < 4; v++) {
            float yv = fmaxf(ylo[v] + sig * (a1[v] - Bc[v]), 0.f);
            ylo[v] = yv;
            _Float16 h = (_Float16)yv;
            yl_hi[(q * 4 + v) * YLS + wc * 16 + lm] = h;
            yl_lo[(q * 4 + v) * YLS + wc * 16 + lm] = (_Float16)(yv - (float)h);
        }
        __syncthreads();   // [A] y_lo planes ready
        // ---- KTy: acc2[16 rows x 128 cols] = Ylo @ S (hi+lo split) ----
        half8 a2h[2], a2l[2];
#pragma unroll
        for (int c = 0; c < 2; c++) {
            a2h[c] = *(const half8*)&yl_hi[lm * YLS + c * 32 + q * 8];
            a2l[c] = *(const half8*)&yl_lo[lm * YLS + c * 32 + q * 8];
        }
        floatx4 acc2[8];
#pragma unroll
        for (int t = 0; t < 8; t++) {
            floatx4 a = {0.f, 0.f, 0.f, 0.f};
#pragma unroll
            for (int c = 0; c < 2; c++) {
                a = __builtin_amdgcn_mfma_f32_16x16x32_f16(a2h[c], s2[t][c], a, 0, 0, 0);
                a = __builtin_amdgcn_mfma_f32_16x16x32_f16(a2l[c], s2[t][c], a, 0, 0, 0);
            }
            acc2[t] = a;
        }
        // ---- y_hi update (uses prev xbar), norm partials ----
        float pn[4] = {0.f, 0.f, 0.f, 0.f};
#pragma unroll
        for (int v = 0; v < 4; v++)
#pragma unroll
            for (int t = 0; t < 8; t++) {
                yhi[v][t] = fmaxf(yhi[v][t] - sig * xb[v][t], 0.f);
                float kty = acc2[t][v] - yhi[v][t];
                float d = x[v][t] - tau * kty + tau - z[v][t];
                pn[v] += d * d;
            }
#pragma unroll
        for (int o = 1; o < 16; o <<= 1)
#pragma unroll
            for (int v = 0; v < 4; v++) pn[v] += __shfl_xor(pn[v], o, 64);
        if (lm == 0)
#pragma unroll
            for (int v = 0; v < 4; v++) red[q * 4 + v][wc] = pn[v];
        __syncthreads();   // [B] norm partials ready
        float scale[4];
#pragma unroll
        for (int v = 0; v < 4; v++) {
            floatx4 r = *(const floatx4*)&red[q * 4 + v][0];
            float nrm = sqrtf(r[0] + r[1] + r[2] + r[3]);
            scale[v] = fmaxf(1.f - tau / fmaxf(nrm, 1e-12f), 0.f);
        }
        // ---- prox + xbar publish ----
#pragma unroll
        for (int v = 0; v < 4; v++)
#pragma unroll
            for (int t = 0; t < 8; t++) {
                float kty = acc2[t][v] - yhi[v][t];
                float d = x[v][t] - tau * kty + tau - z[v][t];
                float xn = z[v][t] + scale[v] * d;
                float xbn = 2.f * xn - x[v][t];
                x[v][t] = xn;
                xb[v][t] = xbn;
                _Float16 h = (_Float16)xbn;
                int a = (q * 4 + v) * XBS + wc * 128 + t * 16 + lm;
                xb_hi[a] = h;
                xb_lo[a] = (_Float16)(xbn - (float)h);
            }
        __syncthreads();   // [C] xbar planes ready for next iteration
    }
#pragma unroll
    for (int v = 0; v < 4; v++)
#pragma unroll
        for (int t = 0; t < 8; t++)
            out[(size_t)(b0 + q * 4 + v) * 512 + wc * 128 + t * 16 + lm] = x[v][t];
}

// ---------------------------------------------------------------------------
extern "C" void kernel_launch(void* const* d_in, const int* in_sizes, int n_in,
                              void* d_out, int out_size, void* d_ws, size_t ws_size,
                              hipStream_t stream) {
    const float* X  = (const float*)d_in[0];
    const float* W1 = (const float*)d_in[1];
    const float* b1 = (const float*)d_in[2];
    const float* W2 = (const float*)d_in[3];
    const float* b2 = (const float*)d_in[4];
    const float* W3 = (const float*)d_in[5];
    const float* b3 = (const float*)d_in[6];
    const float* S  = (const float*)d_in[7];
    float* out = (float*)d_out;

    char* ws = (char*)d_ws;
    size_t off = 0;
    auto alloc = [&](size_t bytes) {
        void* p = ws + off;
        off += (bytes + 255) & ~(size_t)255;
        return p;
    };
    _Float16* Xh  = (_Float16*)alloc((size_t)BATCH * 64 * 2);
    _Float16* W1t = (_Float16*)alloc((size_t)64 * 1024 * 2);
    _Float16* W2t = (_Float16*)alloc((size_t)1024 * 1024 * 2);
    _Float16* W3t = (_Float16*)alloc((size_t)1024 * 512 * 2);
    _Float16* H1  = (_Float16*)alloc((size_t)BATCH * 1024 * 2);
    _Float16* H2  = (_Float16*)alloc((size_t)BATCH * 1024 * 2);
    float*    Zb  = (float*)alloc((size_t)BATCH * 512 * 4);
    _Float16* s1f = (_Float16*)alloc((size_t)4 * 16 * 64 * 8 * 2);
    _Float16* s2f = (_Float16*)alloc((size_t)4 * 8 * 2 * 64 * 8 * 2);
    float*    tau = (float*)alloc(256);

    hipLaunchKernelGGL(cast_x, dim3(512), dim3(256), 0, stream, X, Xh, BATCH * 64);
    hipLaunchKernelGGL(tcast, dim3(32, 2),  dim3(32, 8), 0, stream, W1, W1t, 64, 1024);
    hipLaunchKernelGGL(tcast, dim3(32, 32), dim3(32, 8), 0, stream, W2, W2t, 1024, 1024);
    hipLaunchKernelGGL(tcast, dim3(16, 32), dim3(32, 8), 0, stream, W3, W3t, 1024, 512);
    hipLaunchKernelGGL(build_power, dim3(1), dim3(512), 0, stream, S, s1f, s2f, tau);
    hipLaunchKernelGGL(gemm_relu, dim3(16, 16), dim3(256), 0, stream,
                       Xh, W1t, b1, H1, (float*)nullptr, 1024, 64);
    hipLaunchKernelGGL(gemm_relu, dim3(16, 16), dim3(256), 0, stream,
                       H1, W2t, b2, H2, (float*)nullptr, 1024, 1024);
    hipLaunchKernelGGL(gemm_relu, dim3(8, 16), dim3(256), 0, stream,
                       H2, W3t, b3, (_Float16*)nullptr, Zb, 512, 1024);
    hipLaunchKernelGGL(pdhg_mfma, dim3(BATCH / 16), dim3(256), 0, stream,
                       Zb, X, s1f, s2f, tau, out);
}

// Round 4
// 397.465 us; speedup vs baseline: 5.8845x; 1.1422x over previous
//
#include <hip/hip_runtime.h>

// ---------------------------------------------------------------------------
// MatchNet: 3-layer MLP (relu after every layer) -> batched PDHG LP solve.
// Shapes: X[2048,64], W1[64,1024], W2[1024,1024], W3[1024,512], S[64,512].
// Output: x [2048,512] fp32.
//
// R4: (a) xbar LDS round-trip uses a baked-in K-permutation pi so the C/D->A
// layout transform has contiguous writes (8 ds_write_b128 vs 64 ds_write_b16
// per lane per iter); s1f fragments are built with pi^-1 so MFMA results are
// bit-identical. (b) Kx accumulator split 4 ways (8-deep MFMA chains, not 32).
// (c) build_power split: parallel fragment build + dense LDS power iteration.
// ---------------------------------------------------------------------------

typedef _Float16 half8 __attribute__((ext_vector_type(8)));
typedef float floatx4 __attribute__((ext_vector_type(4)));

#define BATCH 2048
#define NITERS 60
#define XBS 520   // xbar LDS row stride in halves (16B-aligned rows)
#define YLS 72    // ylo  LDS row stride in halves

// ---------------- cast X fp32 -> f16 ----------------
__global__ void cast_x(const float* __restrict__ in, _Float16* __restrict__ out, int n) {
    int i = blockIdx.x * blockDim.x + threadIdx.x;
    if (i < n) out[i] = (_Float16)in[i];
}

// ---------------- transpose + cast W[K][N] fp32 -> Wt[N][K] f16 ----------------
__global__ __launch_bounds__(256) void tcast(const float* __restrict__ W,
                                             _Float16* __restrict__ Wt, int K, int N) {
    __shared__ float tile[32][33];
    int tx = threadIdx.x, ty = threadIdx.y;          // 32 x 8
    int n0 = blockIdx.x * 32, k0 = blockIdx.y * 32;
#pragma unroll
    for (int i = 0; i < 4; i++)
        tile[ty + i * 8][tx] = W[(size_t)(k0 + ty + i * 8) * N + n0 + tx];
    __syncthreads();
#pragma unroll
    for (int i = 0; i < 4; i++)
        Wt[(size_t)(n0 + ty + i * 8) * K + k0 + tx] = (_Float16)tile[tx][ty + i * 8];
}

// ---------------- GEMM: out = relu(A[M,K] @ W[K,N] + bias), A,Wt f16, acc fp32 ----
__global__ __launch_bounds__(256) void gemm_relu(
    const _Float16* __restrict__ A, const _Float16* __restrict__ Wt,
    const float* __restrict__ bias, _Float16* __restrict__ outh,
    float* __restrict__ outf, int N, int K) {
    __shared__ __align__(16) _Float16 As[128][40];
    __shared__ __align__(16) _Float16 Bs[64][40];
    int tid = threadIdx.x;
    int bm = blockIdx.y * 128;
    int bn = blockIdx.x * 64;
    int w = tid >> 6, l = tid & 63;
    int wr = w >> 1, wc = w & 1;
    int lm = l & 15, q = l >> 4;
    floatx4 acc[4][2] = {};

    int ar = tid >> 1;
    int ac = (tid & 1) * 16;
    int br = tid >> 2;
    int bc = (tid & 3) * 8;
    const _Float16* Ag = A + (size_t)(bm + ar) * K;
    const _Float16* Bg = Wt + (size_t)(bn + br) * K;

    for (int k0 = 0; k0 < K; k0 += 32) {
        *(half8*)&As[ar][ac] = *(const half8*)&Ag[k0 + ac];
        *(half8*)&As[ar][ac + 8] = *(const half8*)&Ag[k0 + ac + 8];
        *(half8*)&Bs[br][bc] = *(const half8*)&Bg[k0 + bc];
        __syncthreads();
        half8 af[4], bf[2];
#pragma unroll
        for (int mt = 0; mt < 4; mt++)
            af[mt] = *(const half8*)&As[wr * 64 + mt * 16 + lm][q * 8];
#pragma unroll
        for (int nt = 0; nt < 2; nt++)
            bf[nt] = *(const half8*)&Bs[wc * 32 + nt * 16 + lm][q * 8];
#pragma unroll
        for (int mt = 0; mt < 4; mt++)
#pragma unroll
            for (int nt = 0; nt < 2; nt++)
                acc[mt][nt] = __builtin_amdgcn_mfma_f32_16x16x32_f16(
                    af[mt], bf[nt], acc[mt][nt], 0, 0, 0);
        __syncthreads();
    }
#pragma unroll
    for (int nt = 0; nt < 2; nt++) {
        int col = bn + wc * 32 + nt * 16 + lm;
        float bv = bias[col];
#pragma unroll
        for (int mt = 0; mt < 4; mt++) {
#pragma unroll
            for (int v = 0; v < 4; v++) {
                int row = bm + wr * 64 + mt * 16 + q * 4 + v;
                float val = fmaxf(acc[mt][nt][v] + bv, 0.f);
                if (outh) outh[(size_t)row * N + col] = (_Float16)val;
                else      outf[(size_t)row * N + col] = val;
            }
        }
    }
}

// ---------------- parallel S-fragment build (pi baked into s1f) ----------------
// pi: struct col c = wcb*128 + t*16 + lmc  <->  storage p = wcb*128 + lmc*8 + t.
// s1f (B-frag of S^T for Kx, k-axis = storage order):
//   i = ((wc*16+kk)*64 + lane)*8 + j ; p = kk*32 + (lane>>4)*8 + j
//   value = S[wc*16 + (lane&15)][pi^-1(p)]
// s2f (B-frag of S for KTy, k-axis = combos, unpermuted; n = struct col):
//   i = (((wc*8+t)*2+c)*64 + lane)*8 + j
//   value = S[c*32 + (lane>>4)*8 + j][wc*128 + t*16 + (lane&15)]
__global__ __launch_bounds__(256) void build_frags(
    const float* __restrict__ S, _Float16* __restrict__ s1f,
    _Float16* __restrict__ s2f) {
    int i = blockIdx.x * 256 + threadIdx.x;
    if (i < 4 * 16 * 64 * 8) {
        int j = i & 7, lane = (i >> 3) & 63, kk = (i >> 9) & 15, wc = i >> 13;
        int p = kk * 32 + (lane >> 4) * 8 + j;
        int lmc = (p & 127) >> 3, tc = p & 7;
        int c = (p >> 7) * 128 + tc * 16 + lmc;       // pi^-1
        int m = wc * 16 + (lane & 15);
        s1f[i] = (_Float16)S[m * 512 + c];
    } else {
        int i2 = i - 4 * 16 * 64 * 8;
        int j = i2 & 7, lane = (i2 >> 3) & 63, c = (i2 >> 9) & 1,
            tt = (i2 >> 10) & 7, wc = i2 >> 13;
        int kc = c * 32 + (lane >> 4) * 8 + j;
        int n = wc * 128 + tt * 16 + (lane & 15);
        s2f[i2] = (_Float16)S[kc * 512 + n];
    }
}

// ---------------- dense power iteration for tau (single block, S in LDS u8) ----
__global__ __launch_bounds__(512) void power_iter(
    const float* __restrict__ S, float* __restrict__ tau_g) {
    __shared__ unsigned char Sl[64 * 512];   // 0/1, exact
    __shared__ float vv[512], ww[64], red[8];
    __shared__ float nrm_s;
    int t = threadIdx.x;
    int wv = t >> 6, ln = t & 63;
    for (int i = t; i < 64 * 512; i += 512)
        Sl[i] = (unsigned char)(S[i] != 0.f);
    vv[t] = 0.044194173824159216f;  // 1/sqrt(512)
    __syncthreads();

    for (int s = 0; s <= 30; s++) {
        // w = S v : wave wv does rows wv*8..+8; lane partial over 8 chunks
        float pr[8];
#pragma unroll
        for (int rr = 0; rr < 8; rr++) {
            int r = wv * 8 + rr;
            float a = 0.f;
#pragma unroll
            for (int e = 0; e < 8; e++)
                a += (float)Sl[r * 512 + e * 64 + ln] * vv[e * 64 + ln];
            pr[rr] = a;
        }
#pragma unroll
        for (int o = 32; o > 0; o >>= 1)
#pragma unroll
            for (int rr = 0; rr < 8; rr++) pr[rr] += __shfl_xor(pr[rr], o, 64);
        if (ln < 8) ww[wv * 8 + ln] = pr[ln];   // lane rr==ln holds full sum
        __syncthreads();
        // u = v + S^T w : thread t owns struct col t
        float u = vv[t];
#pragma unroll
        for (int j = 0; j < 64; j++) u += (float)Sl[j * 512 + t] * ww[j];
        if (s == 30) {
            // L^2 = v . u with normalized v
            float n2 = vv[t] * u;
#pragma unroll
            for (int o = 32; o > 0; o >>= 1) n2 += __shfl_xor(n2, o, 64);
            if (ln == 0) red[wv] = n2;
            __syncthreads();
            if (t == 0) {
                float tot = 0.f;
                for (int qq = 0; qq < 8; qq++) tot += red[qq];
                tau_g[0] = 0.9f / sqrtf(tot);
            }
            return;
        }
        float n2 = u * u;
#pragma unroll
        for (int o = 32; o > 0; o >>= 1) n2 += __shfl_xor(n2, o, 64);
        if (ln == 0) red[wv] = n2;
        __syncthreads();
        if (t == 0) {
            float tot = 0.f;
            for (int qq = 0; qq < 8; qq++) tot += red[qq];
            nrm_s = sqrtf(tot);
        }
        __syncthreads();
        vv[t] = u / nrm_s;
        __syncthreads();
    }
}

// ---------------- MFMA-dense 60-iteration PDHG ---------------------------------
// Workgroup = 16 batch rows, 4 waves; wave wc owns combos [wc*16,+16) and
// struct cols [wc*128,+128). xbar LDS planes are stored in pi-order so the
// epilogue writes one half8 per (v,plane): 8 ds_write_b128/lane/iter.
__global__ __launch_bounds__(256, 1) void pdhg_mfma(
    const float* __restrict__ Zb, const float* __restrict__ Xf,
    const _Float16* __restrict__ s1f, const _Float16* __restrict__ s2f,
    const float* __restrict__ tau_p, float* __restrict__ out) {
    __shared__ __align__(16) _Float16 xb_hi[16 * XBS];
    __shared__ __align__(16) _Float16 xb_lo[16 * XBS];
    __shared__ __align__(16) _Float16 yl_hi[16 * YLS];
    __shared__ __align__(16) _Float16 yl_lo[16 * YLS];
    __shared__ __align__(16) float red[16][4];
    int tid = threadIdx.x;
    int wc = tid >> 6, l = tid & 63, lm = l & 15, q = l >> 4;
    int b0 = blockIdx.x * 16;

    // constant S fragments -> registers (held across all 60 iterations)
    half8 s1[16], s2[8][2];
#pragma unroll
    for (int kk = 0; kk < 16; kk++)
        s1[kk] = *(const half8*)&s1f[((wc * 16 + kk) * 64 + l) * 8];
#pragma unroll
    for (int t = 0; t < 8; t++)
#pragma unroll
        for (int c = 0; c < 2; c++)
            s2[t][c] = *(const half8*)&s2f[(((wc * 8 + t) * 2 + c) * 64 + l) * 8];

    float z[4][8], x[4][8], xb[4][8], yhi[4][8];
    floatx4 ylo, Bc;
#pragma unroll
    for (int v = 0; v < 4; v++) {
        int row = b0 + q * 4 + v;
        Bc[v] = Xf[row * 64 + wc * 16 + lm];
        ylo[v] = 0.f;
#pragma unroll
        for (int t = 0; t < 8; t++) {
            z[v][t] = Zb[(size_t)row * 512 + wc * 128 + t * 16 + lm];
            x[v][t] = 0.f; xb[v][t] = 0.f; yhi[v][t] = 0.f;
        }
    }
    {
        half8 hz = {0, 0, 0, 0, 0, 0, 0, 0};
        for (int i = tid; i < (16 * XBS) / 8; i += 256) {
            *(half8*)&xb_hi[i * 8] = hz;
            *(half8*)&xb_lo[i * 8] = hz;
        }
    }
    float tau = tau_p[0];
    float sig = tau;
    __syncthreads();

#pragma unroll 1
    for (int it = 0; it < NITERS; ++it) {
        // ---- Kx: a1[16 rows x 16 combos] = Xbar @ S^T (hi+lo, 4 acc chains) ----
        floatx4 aacc[4] = {{0.f,0.f,0.f,0.f},{0.f,0.f,0.f,0.f},
                           {0.f,0.f,0.f,0.f},{0.f,0.f,0.f,0.f}};
#pragma unroll
        for (int kk = 0; kk < 16; kk++) {
            half8 ah = *(const half8*)&xb_hi[lm * XBS + kk * 32 + q * 8];
            half8 al = *(const half8*)&xb_lo[lm * XBS + kk * 32 + q * 8];
            aacc[kk & 3] = __builtin_amdgcn_mfma_f32_16x16x32_f16(ah, s1[kk], aacc[kk & 3], 0, 0, 0);
            aacc[kk & 3] = __builtin_amdgcn_mfma_f32_16x16x32_f16(al, s1[kk], aacc[kk & 3], 0, 0, 0);
        }
        floatx4 a1 = (aacc[0] + aacc[1]) + (aacc[2] + aacc[3]);
        // ---- y_lo update + publish hi/lo planes ----
#pragma unroll
        for (int v = 0; v < 4; v++) {
            float yv = fmaxf(ylo[v] + sig * (a1[v] - Bc[v]), 0.f);
            ylo[v] = yv;
            _Float16 h = (_Float16)yv;
            yl_hi[(q * 4 + v) * YLS + wc * 16 + lm] = h;
            yl_lo[(q * 4 + v) * YLS + wc * 16 + lm] = (_Float16)(yv - (float)h);
        }
        __syncthreads();   // [A] y_lo planes ready
        // ---- KTy: acc2[16 rows x 128 cols] = Ylo @ S (hi+lo split) ----
        half8 a2h[2], a2l[2];
#pragma unroll
        for (int c = 0; c < 2; c++) {
            a2h[c] = *(const half8*)&yl_hi[lm * YLS + c * 32 + q * 8];
            a2l[c] = *(const half8*)&yl_lo[lm * YLS + c * 32 + q * 8];
        }
        floatx4 acc2[8];
#pragma unroll
        for (int t = 0; t < 8; t++) {
            floatx4 a = {0.f, 0.f, 0.f, 0.f};
#pragma unroll
            for (int c = 0; c < 2; c++) {
                a = __builtin_amdgcn_mfma_f32_16x16x32_f16(a2h[c], s2[t][c], a, 0, 0, 0);
                a = __builtin_amdgcn_mfma_f32_16x16x32_f16(a2l[c], s2[t][c], a, 0, 0, 0);
            }
            acc2[t] = a;
        }
        // ---- y_hi update (uses prev xbar), norm partials ----
        float pn[4] = {0.f, 0.f, 0.f, 0.f};
#pragma unroll
        for (int v = 0; v < 4; v++)
#pragma unroll
            for (int t = 0; t < 8; t++) {
                yhi[v][t] = fmaxf(yhi[v][t] - sig * xb[v][t], 0.f);
                float kty = acc2[t][v] - yhi[v][t];
                float d = x[v][t] - tau * kty + tau - z[v][t];
                pn[v] += d * d;
            }
#pragma unroll
        for (int o = 1; o < 16; o <<= 1)
#pragma unroll
            for (int v = 0; v < 4; v++) pn[v] += __shfl_xor(pn[v], o, 64);
        if (lm == 0)
#pragma unroll
            for (int v = 0; v < 4; v++) red[q * 4 + v][wc] = pn[v];
        __syncthreads();   // [B] norm partials ready
        float scale[4];
#pragma unroll
        for (int v = 0; v < 4; v++) {
            floatx4 r = *(const floatx4*)&red[q * 4 + v][0];
            float nrm = sqrtf(r[0] + r[1] + r[2] + r[3]);
            scale[v] = fmaxf(1.f - tau / fmaxf(nrm, 1e-12f), 0.f);
        }
        // ---- prox + xbar publish (pi-order: one half8 per plane per v) ----
#pragma unroll
        for (int v = 0; v < 4; v++) {
            half8 hv, hl;
#pragma unroll
            for (int t = 0; t < 8; t++) {
                float kty = acc2[t][v] - yhi[v][t];
                float d = x[v][t] - tau * kty + tau - z[v][t];
                float xn = z[v][t] + scale[v] * d;
                float xbn = 2.f * xn - x[v][t];
                x[v][t] = xn;
                xb[v][t] = xbn;
                _Float16 h = (_Float16)xbn;
                hv[t] = h;
                hl[t] = (_Float16)(xbn - (float)h);
            }
            int base = (q * 4 + v) * XBS + wc * 128 + lm * 8;   // pi(col)
            *(half8*)&xb_hi[base] = hv;
            *(half8*)&xb_lo[base] = hl;
        }
        __syncthreads();   // [C] xbar planes ready for next iteration
    }
#pragma unroll
    for (int v = 0; v < 4; v++)
#pragma unroll
        for (int t = 0; t < 8; t++)
            out[(size_t)(b0 + q * 4 + v) * 512 + wc * 128 + t * 16 + lm] = x[v][t];
}

// ---------------------------------------------------------------------------
extern "C" void kernel_launch(void* const* d_in, const int* in_sizes, int n_in,
                              void* d_out, int out_size, void* d_ws, size_t ws_size,
                              hipStream_t stream) {
    const float* X  = (const float*)d_in[0];
    const float* W1 = (const float*)d_in[1];
    const float* b1 = (const float*)d_in[2];
    const float* W2 = (const float*)d_in[3];
    const float* b2 = (const float*)d_in[4];
    const float* W3 = (const float*)d_in[5];
    const float* b3 = (const float*)d_in[6];
    const float* S  = (const float*)d_in[7];
    float* out = (float*)d_out;

    char* ws = (char*)d_ws;
    size_t off = 0;
    auto alloc = [&](size_t bytes) {
        void* p = ws + off;
        off += (bytes + 255) & ~(size_t)255;
        return p;
    };
    _Float16* Xh  = (_Float16*)alloc((size_t)BATCH * 64 * 2);
    _Float16* W1t = (_Float16*)alloc((size_t)64 * 1024 * 2);
    _Float16* W2t = (_Float16*)alloc((size_t)1024 * 1024 * 2);
    _Float16* W3t = (_Float16*)alloc((size_t)1024 * 512 * 2);
    _Float16* H1  = (_Float16*)alloc((size_t)BATCH * 1024 * 2);
    _Float16* H2  = (_Float16*)alloc((size_t)BATCH * 1024 * 2);
    float*    Zb  = (float*)alloc((size_t)BATCH * 512 * 4);
    _Float16* s1f = (_Float16*)alloc((size_t)4 * 16 * 64 * 8 * 2);
    _Float16* s2f = (_Float16*)alloc((size_t)4 * 8 * 2 * 64 * 8 * 2);
    float*    tau = (float*)alloc(256);

    hipLaunchKernelGGL(cast_x, dim3(512), dim3(256), 0, stream, X, Xh, BATCH * 64);
    hipLaunchKernelGGL(tcast, dim3(32, 2),  dim3(32, 8), 0, stream, W1, W1t, 64, 1024);
    hipLaunchKernelGGL(tcast, dim3(32, 32), dim3(32, 8), 0, stream, W2, W2t, 1024, 1024);
    hipLaunchKernelGGL(tcast, dim3(16, 32), dim3(32, 8), 0, stream, W3, W3t, 1024, 512);
    hipLaunchKernelGGL(build_frags, dim3((4*16*64*8 + 4*8*2*64*8) / 256), dim3(256), 0,
                       stream, S, s1f, s2f);
    hipLaunchKernelGGL(power_iter, dim3(1), dim3(512), 0, stream, S, tau);
    hipLaunchKernelGGL(gemm_relu, dim3(16, 16), dim3(256), 0, stream,
                       Xh, W1t, b1, H1, (float*)nullptr, 1024, 64);
    hipLaunchKernelGGL(gemm_relu, dim3(16, 16), dim3(256), 0, stream,
                       H1, W2t, b2, H2, (float*)nullptr, 1024, 1024);
    hipLaunchKernelGGL(gemm_relu, dim3(8, 16), dim3(256), 0, stream,
                       H2, W3t, b3, (_Float16*)nullptr, Zb, 512, 1024);
    hipLaunchKernelGGL(pdhg_mfma, dim3(BATCH / 16), dim3(256), 0, stream,
                       Zb, X, s1f, s2f, tau, out);
}

// Round 5
// 372.816 us; speedup vs baseline: 6.2736x; 1.0661x over previous
//
#include <hip/hip_runtime.h>

// ---------------------------------------------------------------------------
// MatchNet: 3-layer MLP (relu after every layer) -> batched PDHG LP solve.
// Shapes: X[2048,64], W1[64,1024], W2[1024,1024], W3[1024,512], S[64,512].
// Output: x [2048,512] fp32.
//
// R5: Delta-form PDHG. K is linear, so keep running fp32 accumulators
//   a1  = S  . xbar_pub   (per-wave 16-combo C/D tile, persistent)
//   acc2= S^T. ylo_pub    (per-wave 128-col C/D tile, persistent)
// and per iteration publish only fl16(delta) planes to LDS, accumulating
//   a1 += S.d_xbar, acc2 += S^T.d_y  via MFMA (C carried in fp32/AGPR).
// Error is a path-length bound 2^-11 * sum|delta| (delta decays geometrically)
// vs R4's per-iter absolute hi/lo. Halves LDS reads, MFMAs, and xbar writes.
// ---------------------------------------------------------------------------

typedef _Float16 half8 __attribute__((ext_vector_type(8)));
typedef float floatx4 __attribute__((ext_vector_type(4)));

#define BATCH 2048
#define NITERS 60
#define XBS 520   // delta-xbar LDS row stride in halves (16B-aligned rows)
#define YLS 72    // delta-ylo  LDS row stride in halves

// ---------------- cast X fp32 -> f16 ----------------
__global__ void cast_x(const float* __restrict__ in, _Float16* __restrict__ out, int n) {
    int i = blockIdx.x * blockDim.x + threadIdx.x;
    if (i < n) out[i] = (_Float16)in[i];
}

// ---------------- transpose + cast W[K][N] fp32 -> Wt[N][K] f16 ----------------
__global__ __launch_bounds__(256) void tcast(const float* __restrict__ W,
                                             _Float16* __restrict__ Wt, int K, int N) {
    __shared__ float tile[32][33];
    int tx = threadIdx.x, ty = threadIdx.y;          // 32 x 8
    int n0 = blockIdx.x * 32, k0 = blockIdx.y * 32;
#pragma unroll
    for (int i = 0; i < 4; i++)
        tile[ty + i * 8][tx] = W[(size_t)(k0 + ty + i * 8) * N + n0 + tx];
    __syncthreads();
#pragma unroll
    for (int i = 0; i < 4; i++)
        Wt[(size_t)(n0 + ty + i * 8) * K + k0 + tx] = (_Float16)tile[tx][ty + i * 8];
}

// ---------------- GEMM: out = relu(A[M,K] @ W[K,N] + bias), A,Wt f16, acc fp32 ----
__global__ __launch_bounds__(256) void gemm_relu(
    const _Float16* __restrict__ A, const _Float16* __restrict__ Wt,
    const float* __restrict__ bias, _Float16* __restrict__ outh,
    float* __restrict__ outf, int N, int K) {
    __shared__ __align__(16) _Float16 As[128][40];
    __shared__ __align__(16) _Float16 Bs[64][40];
    int tid = threadIdx.x;
    int bm = blockIdx.y * 128;
    int bn = blockIdx.x * 64;
    int w = tid >> 6, l = tid & 63;
    int wr = w >> 1, wc = w & 1;
    int lm = l & 15, q = l >> 4;
    floatx4 acc[4][2] = {};

    int ar = tid >> 1;
    int ac = (tid & 1) * 16;
    int br = tid >> 2;
    int bc = (tid & 3) * 8;
    const _Float16* Ag = A + (size_t)(bm + ar) * K;
    const _Float16* Bg = Wt + (size_t)(bn + br) * K;

    for (int k0 = 0; k0 < K; k0 += 32) {
        *(half8*)&As[ar][ac] = *(const half8*)&Ag[k0 + ac];
        *(half8*)&As[ar][ac + 8] = *(const half8*)&Ag[k0 + ac + 8];
        *(half8*)&Bs[br][bc] = *(const half8*)&Bg[k0 + bc];
        __syncthreads();
        half8 af[4], bf[2];
#pragma unroll
        for (int mt = 0; mt < 4; mt++)
            af[mt] = *(const half8*)&As[wr * 64 + mt * 16 + lm][q * 8];
#pragma unroll
        for (int nt = 0; nt < 2; nt++)
            bf[nt] = *(const half8*)&Bs[wc * 32 + nt * 16 + lm][q * 8];
#pragma unroll
        for (int mt = 0; mt < 4; mt++)
#pragma unroll
            for (int nt = 0; nt < 2; nt++)
                acc[mt][nt] = __builtin_amdgcn_mfma_f32_16x16x32_f16(
                    af[mt], bf[nt], acc[mt][nt], 0, 0, 0);
        __syncthreads();
    }
#pragma unroll
    for (int nt = 0; nt < 2; nt++) {
        int col = bn + wc * 32 + nt * 16 + lm;
        float bv = bias[col];
#pragma unroll
        for (int mt = 0; mt < 4; mt++) {
#pragma unroll
            for (int v = 0; v < 4; v++) {
                int row = bm + wr * 64 + mt * 16 + q * 4 + v;
                float val = fmaxf(acc[mt][nt][v] + bv, 0.f);
                if (outh) outh[(size_t)row * N + col] = (_Float16)val;
                else      outf[(size_t)row * N + col] = val;
            }
        }
    }
}

// ---------------- parallel S-fragment build (pi baked into s1f) ----------------
// pi: struct col c = wcb*128 + t*16 + lmc  <->  storage p = wcb*128 + lmc*8 + t.
__global__ __launch_bounds__(256) void build_frags(
    const float* __restrict__ S, _Float16* __restrict__ s1f,
    _Float16* __restrict__ s2f) {
    int i = blockIdx.x * 256 + threadIdx.x;
    if (i < 4 * 16 * 64 * 8) {
        int j = i & 7, lane = (i >> 3) & 63, kk = (i >> 9) & 15, wc = i >> 13;
        int p = kk * 32 + (lane >> 4) * 8 + j;
        int lmc = (p & 127) >> 3, tc = p & 7;
        int c = (p >> 7) * 128 + tc * 16 + lmc;       // pi^-1
        int m = wc * 16 + (lane & 15);
        s1f[i] = (_Float16)S[m * 512 + c];
    } else {
        int i2 = i - 4 * 16 * 64 * 8;
        int j = i2 & 7, lane = (i2 >> 3) & 63, c = (i2 >> 9) & 1,
            tt = (i2 >> 10) & 7, wc = i2 >> 13;
        int kc = c * 32 + (lane >> 4) * 8 + j;
        int n = wc * 128 + tt * 16 + (lane & 15);
        s2f[i2] = (_Float16)S[kc * 512 + n];
    }
}

// ---------------- dense power iteration for tau (single block, S in LDS u8) ----
__global__ __launch_bounds__(512) void power_iter(
    const float* __restrict__ S, float* __restrict__ tau_g) {
    __shared__ unsigned char Sl[64 * 512];   // 0/1, exact
    __shared__ float vv[512], ww[64], red[8];
    __shared__ float nrm_s;
    int t = threadIdx.x;
    int wv = t >> 6, ln = t & 63;
    for (int i = t; i < 64 * 512; i += 512)
        Sl[i] = (unsigned char)(S[i] != 0.f);
    vv[t] = 0.044194173824159216f;  // 1/sqrt(512)
    __syncthreads();

    for (int s = 0; s <= 30; s++) {
        float pr[8];
#pragma unroll
        for (int rr = 0; rr < 8; rr++) {
            int r = wv * 8 + rr;
            float a = 0.f;
#pragma unroll
            for (int e = 0; e < 8; e++)
                a += (float)Sl[r * 512 + e * 64 + ln] * vv[e * 64 + ln];
            pr[rr] = a;
        }
#pragma unroll
        for (int o = 32; o > 0; o >>= 1)
#pragma unroll
            for (int rr = 0; rr < 8; rr++) pr[rr] += __shfl_xor(pr[rr], o, 64);
        if (ln < 8) ww[wv * 8 + ln] = pr[ln];
        __syncthreads();
        float u = vv[t];
#pragma unroll
        for (int j = 0; j < 64; j++) u += (float)Sl[j * 512 + t] * ww[j];
        if (s == 30) {
            float n2 = vv[t] * u;
#pragma unroll
            for (int o = 32; o > 0; o >>= 1) n2 += __shfl_xor(n2, o, 64);
            if (ln == 0) red[wv] = n2;
            __syncthreads();
            if (t == 0) {
                float tot = 0.f;
                for (int qq = 0; qq < 8; qq++) tot += red[qq];
                tau_g[0] = 0.9f / sqrtf(tot);
            }
            return;
        }
        float n2 = u * u;
#pragma unroll
        for (int o = 32; o > 0; o >>= 1) n2 += __shfl_xor(n2, o, 64);
        if (ln == 0) red[wv] = n2;
        __syncthreads();
        if (t == 0) {
            float tot = 0.f;
            for (int qq = 0; qq < 8; qq++) tot += red[qq];
            nrm_s = sqrtf(tot);
        }
        __syncthreads();
        vv[t] = u / nrm_s;
        __syncthreads();
    }
}

// ---------------- Delta-form MFMA PDHG, 60 iterations ---------------------------
// Workgroup = 16 batch rows, 4 waves; wave wc owns combos [wc*16,+16) and
// struct cols [wc*128,+128). Running fp32 accumulators: a1p (S.xbar, 4 split
// chains) and acc2 (S^T.ylo). Published LDS planes carry fl16 deltas only.
__global__ __launch_bounds__(256, 1) void pdhg_mfma(
    const float* __restrict__ Zb, const float* __restrict__ Xf,
    const _Float16* __restrict__ s1f, const _Float16* __restrict__ s2f,
    const float* __restrict__ tau_p, float* __restrict__ out) {
    __shared__ __align__(16) _Float16 xb_d[16 * XBS];   // delta-xbar, pi-order
    __shared__ __align__(16) _Float16 yl_d[16 * YLS];   // delta-ylo
    __shared__ __align__(16) float red[16][4];
    int tid = threadIdx.x;
    int wc = tid >> 6, l = tid & 63, lm = l & 15, q = l >> 4;
    int b0 = blockIdx.x * 16;

    // constant S fragments -> registers (held across all 60 iterations)
    half8 s1[16], s2[8][2];
#pragma unroll
    for (int kk = 0; kk < 16; kk++)
        s1[kk] = *(const half8*)&s1f[((wc * 16 + kk) * 64 + l) * 8];
#pragma unroll
    for (int t = 0; t < 8; t++)
#pragma unroll
        for (int c = 0; c < 2; c++)
            s2[t][c] = *(const half8*)&s2f[(((wc * 8 + t) * 2 + c) * 64 + l) * 8];

    float z[4][8], x[4][8], xb[4][8], yhi[4][8];
    floatx4 ylo, Bc;
    floatx4 a1p[4] = {{0.f,0.f,0.f,0.f},{0.f,0.f,0.f,0.f},
                      {0.f,0.f,0.f,0.f},{0.f,0.f,0.f,0.f}};   // running S.xbar
    floatx4 acc2[8];                                          // running S^T.ylo
#pragma unroll
    for (int t = 0; t < 8; t++) acc2[t] = floatx4{0.f, 0.f, 0.f, 0.f};
#pragma unroll
    for (int v = 0; v < 4; v++) {
        int row = b0 + q * 4 + v;
        Bc[v] = Xf[row * 64 + wc * 16 + lm];
        ylo[v] = 0.f;
#pragma unroll
        for (int t = 0; t < 8; t++) {
            z[v][t] = Zb[(size_t)row * 512 + wc * 128 + t * 16 + lm];
            x[v][t] = 0.f; xb[v][t] = 0.f; yhi[v][t] = 0.f;
        }
    }
    {
        half8 hz = {0, 0, 0, 0, 0, 0, 0, 0};
        for (int i = tid; i < (16 * XBS) / 8; i += 256)
            *(half8*)&xb_d[i * 8] = hz;
    }
    float tau = tau_p[0];
    float sig = tau;
    __syncthreads();

#pragma unroll 1
    for (int it = 0; it < NITERS; ++it) {
        // ---- Kx increment: a1p += d_xbar @ S^T (single f16 delta plane) ----
#pragma unroll
        for (int kk = 0; kk < 16; kk++) {
            half8 ad = *(const half8*)&xb_d[lm * XBS + kk * 32 + q * 8];
            a1p[kk & 3] = __builtin_amdgcn_mfma_f32_16x16x32_f16(ad, s1[kk], a1p[kk & 3], 0, 0, 0);
        }
        floatx4 a1 = (a1p[0] + a1p[1]) + (a1p[2] + a1p[3]);  // = S.xbar_pub
        // ---- y_lo update + publish delta ----
#pragma unroll
        for (int v = 0; v < 4; v++) {
            float yv = fmaxf(ylo[v] + sig * (a1[v] - Bc[v]), 0.f);
            float dy = yv - ylo[v];
            ylo[v] = yv;
            yl_d[(q * 4 + v) * YLS + wc * 16 + lm] = (_Float16)dy;
        }
        __syncthreads();   // [A] delta-y plane ready
        // ---- KTy increment: acc2 += d_y @ S ----
        half8 a2d[2];
#pragma unroll
        for (int c = 0; c < 2; c++)
            a2d[c] = *(const half8*)&yl_d[lm * YLS + c * 32 + q * 8];
#pragma unroll
        for (int t = 0; t < 8; t++)
#pragma unroll
            for (int c = 0; c < 2; c++)
                acc2[t] = __builtin_amdgcn_mfma_f32_16x16x32_f16(a2d[c], s2[t][c], acc2[t], 0, 0, 0);
        // ---- y_hi update (uses prev xbar), norm partials ----
        float pn[4] = {0.f, 0.f, 0.f, 0.f};
#pragma unroll
        for (int v = 0; v < 4; v++)
#pragma unroll
            for (int t = 0; t < 8; t++) {
                yhi[v][t] = fmaxf(yhi[v][t] - sig * xb[v][t], 0.f);
                float kty = acc2[t][v] - yhi[v][t];
                float d = x[v][t] - tau * kty + tau - z[v][t];
                pn[v] += d * d;
            }
#pragma unroll
        for (int o = 1; o < 16; o <<= 1)
#pragma unroll
            for (int v = 0; v < 4; v++) pn[v] += __shfl_xor(pn[v], o, 64);
        if (lm == 0)
#pragma unroll
            for (int v = 0; v < 4; v++) red[q * 4 + v][wc] = pn[v];
        __syncthreads();   // [B] norm partials ready
        float scale[4];
#pragma unroll
        for (int v = 0; v < 4; v++) {
            floatx4 r = *(const floatx4*)&red[q * 4 + v][0];
            float nrm = sqrtf(r[0] + r[1] + r[2] + r[3]);
            scale[v] = fmaxf(1.f - tau / fmaxf(nrm, 1e-12f), 0.f);
        }
        // ---- prox + delta-xbar publish (pi-order, one half8 per v) ----
#pragma unroll
        for (int v = 0; v < 4; v++) {
            half8 hd;
#pragma unroll
            for (int t = 0; t < 8; t++) {
                float kty = acc2[t][v] - yhi[v][t];
                float d = x[v][t] - tau * kty + tau - z[v][t];
                float xn = z[v][t] + scale[v] * d;
                float xbn = 2.f * xn - x[v][t];
                hd[t] = (_Float16)(xbn - xb[v][t]);   // delta
                x[v][t] = xn;
                xb[v][t] = xbn;
            }
            *(half8*)&xb_d[(q * 4 + v) * XBS + wc * 128 + lm * 8] = hd;
        }
        __syncthreads();   // [C] delta-xbar plane ready for next iteration
    }
#pragma unroll
    for (int v = 0; v < 4; v++)
#pragma unroll
        for (int t = 0; t < 8; t++)
            out[(size_t)(b0 + q * 4 + v) * 512 + wc * 128 + t * 16 + lm] = x[v][t];
}

// ---------------------------------------------------------------------------
extern "C" void kernel_launch(void* const* d_in, const int* in_sizes, int n_in,
                              void* d_out, int out_size, void* d_ws, size_t ws_size,
                              hipStream_t stream) {
    const float* X  = (const float*)d_in[0];
    const float* W1 = (const float*)d_in[1];
    const float* b1 = (const float*)d_in[2];
    const float* W2 = (const float*)d_in[3];
    const float* b2 = (const float*)d_in[4];
    const float* W3 = (const float*)d_in[5];
    const float* b3 = (const float*)d_in[6];
    const float* S  = (const float*)d_in[7];
    float* out = (float*)d_out;

    char* ws = (char*)d_ws;
    size_t off = 0;
    auto alloc = [&](size_t bytes) {
        void* p = ws + off;
        off += (bytes + 255) & ~(size_t)255;
        return p;
    };
    _Float16* Xh  = (_Float16*)alloc((size_t)BATCH * 64 * 2);
    _Float16* W1t = (_Float16*)alloc((size_t)64 * 1024 * 2);
    _Float16* W2t = (_Float16*)alloc((size_t)1024 * 1024 * 2);
    _Float16* W3t = (_Float16*)alloc((size_t)1024 * 512 * 2);
    _Float16* H1  = (_Float16*)alloc((size_t)BATCH * 1024 * 2);
    _Float16* H2  = (_Float16*)alloc((size_t)BATCH * 1024 * 2);
    float*    Zb  = (float*)alloc((size_t)BATCH * 512 * 4);
    _Float16* s1f = (_Float16*)alloc((size_t)4 * 16 * 64 * 8 * 2);
    _Float16* s2f = (_Float16*)alloc((size_t)4 * 8 * 2 * 64 * 8 * 2);
    float*    tau = (float*)alloc(256);

    hipLaunchKernelGGL(cast_x, dim3(512), dim3(256), 0, stream, X, Xh, BATCH * 64);
    hipLaunchKernelGGL(tcast, dim3(32, 2),  dim3(32, 8), 0, stream, W1, W1t, 64, 1024);
    hipLaunchKernelGGL(tcast, dim3(32, 32), dim3(32, 8), 0, stream, W2, W2t, 1024, 1024);
    hipLaunchKernelGGL(tcast, dim3(16, 32), dim3(32, 8), 0, stream, W3, W3t, 1024, 512);
    hipLaunchKernelGGL(build_frags, dim3((4*16*64*8 + 4*8*2*64*8) / 256), dim3(256), 0,
                       stream, S, s1f, s2f);
    hipLaunchKernelGGL(power_iter, dim3(1), dim3(512), 0, stream, S, tau);
    hipLaunchKernelGGL(gemm_relu, dim3(16, 16), dim3(256), 0, stream,
                       Xh, W1t, b1, H1, (float*)nullptr, 1024, 64);
    hipLaunchKernelGGL(gemm_relu, dim3(16, 16), dim3(256), 0, stream,
                       H1, W2t, b2, H2, (float*)nullptr, 1024, 1024);
    hipLaunchKernelGGL(gemm_relu, dim3(8, 16), dim3(256), 0, stream,
                       H2, W3t, b3, (_Float16*)nullptr, Zb, 512, 1024);
    hipLaunchKernelGGL(pdhg_mfma, dim3(BATCH / 16), dim3(256), 0, stream,
                       Zb, X, s1f, s2f, tau, out);
}

// Round 6
// 359.516 us; speedup vs baseline: 6.5057x; 1.0370x over previous
//
#include <hip/hip_runtime.h>

// ---------------------------------------------------------------------------
// MatchNet: 3-layer MLP (relu after every layer) -> batched PDHG LP solve.
// Shapes: X[2048,64], W1[64,1024], W2[1024,1024], W3[1024,512], S[64,512].
// Output: x [2048,512] fp32.
//
// R6: (a) pdhg uses 8-batch-row tiles (grid 256 -> all CUs active; MFMA rows
// 8..15 are permanently-zero padding, lanes q>=2 predicated off publishes).
// (b) gemm_relu stages A/B tiles via __builtin_amdgcn_global_load_lds width=16
// (wave-uniform LDS base + lane*16; unpadded [rows][32] LDS layout).
// ---------------------------------------------------------------------------

typedef _Float16 half8 __attribute__((ext_vector_type(8)));
typedef float floatx4 __attribute__((ext_vector_type(4)));

#define BATCH 2048
#define NITERS 60
#define XBS 520   // delta-xbar LDS row stride in halves (16B-aligned rows)
#define YLS 72    // delta-ylo  LDS row stride in halves

typedef const __attribute__((address_space(1))) unsigned int* gptr_as1;
typedef __attribute__((address_space(3))) unsigned int* lptr_as3;
__device__ __forceinline__ void gl_lds16(const _Float16* g, _Float16* s) {
    // async global->LDS, 16B/lane; LDS dest = wave-uniform base + lane*16
    __builtin_amdgcn_global_load_lds((gptr_as1)g, (lptr_as3)s, 16, 0, 0);
}

// ---------------- cast X fp32 -> f16 ----------------
__global__ void cast_x(const float* __restrict__ in, _Float16* __restrict__ out, int n) {
    int i = blockIdx.x * blockDim.x + threadIdx.x;
    if (i < n) out[i] = (_Float16)in[i];
}

// ---------------- transpose + cast W[K][N] fp32 -> Wt[N][K] f16 ----------------
__global__ __launch_bounds__(256) void tcast(const float* __restrict__ W,
                                             _Float16* __restrict__ Wt, int K, int N) {
    __shared__ float tile[32][33];
    int tx = threadIdx.x, ty = threadIdx.y;          // 32 x 8
    int n0 = blockIdx.x * 32, k0 = blockIdx.y * 32;
#pragma unroll
    for (int i = 0; i < 4; i++)
        tile[ty + i * 8][tx] = W[(size_t)(k0 + ty + i * 8) * N + n0 + tx];
    __syncthreads();
#pragma unroll
    for (int i = 0; i < 4; i++)
        Wt[(size_t)(n0 + ty + i * 8) * K + k0 + tx] = (_Float16)tile[tx][ty + i * 8];
}

// ---------------- GEMM: out = relu(A[M,K] @ W[K,N] + bias), A,Wt f16, acc fp32 ----
// Staging via global_load_lds (16B/lane). LDS unpadded [rows][32] halves: b128
// frag reads at 64B row stride are phase-aligned (m97 structure).
__global__ __launch_bounds__(256) void gemm_relu(
    const _Float16* __restrict__ A, const _Float16* __restrict__ Wt,
    const float* __restrict__ bias, _Float16* __restrict__ outh,
    float* __restrict__ outf, int N, int K) {
    __shared__ __align__(16) _Float16 As[128 * 32];
    __shared__ __align__(16) _Float16 Bs[64 * 32];
    int tid = threadIdx.x;
    int bm = blockIdx.y * 128;
    int bn = blockIdx.x * 64;
    int w = tid >> 6, l = tid & 63;
    int wr = w >> 1, wc = w & 1;
    int lm = l & 15, q = l >> 4;
    floatx4 acc[4][2] = {};

    int sr = l >> 2;            // row within 16-row staging chunk
    int sc = (l & 3) * 8;       // half offset within 32-half row
    // A: wave w stages rows [w*32, w*32+32) as two 1KB chunks
    const _Float16* ag0 = A + (size_t)(bm + w * 32 + sr) * K + sc;
    const _Float16* ag1 = A + (size_t)(bm + w * 32 + 16 + sr) * K + sc;
    _Float16* as0 = &As[(w * 32) * 32];
    _Float16* as1 = &As[(w * 32 + 16) * 32];
    // B: wave w stages rows [w*16, w*16+16)
    const _Float16* bg = Wt + (size_t)(bn + w * 16 + sr) * K + sc;
    _Float16* bs = &Bs[(w * 16) * 32];

    for (int k0 = 0; k0 < K; k0 += 32) {
        gl_lds16(ag0 + k0, as0);
        gl_lds16(ag1 + k0, as1);
        gl_lds16(bg + k0, bs);
        __syncthreads();   // drains vmcnt -> staging visible
        half8 af[4], bf[2];
#pragma unroll
        for (int mt = 0; mt < 4; mt++)
            af[mt] = *(const half8*)&As[(wr * 64 + mt * 16 + lm) * 32 + q * 8];
#pragma unroll
        for (int nt = 0; nt < 2; nt++)
            bf[nt] = *(const half8*)&Bs[(wc * 32 + nt * 16 + lm) * 32 + q * 8];
#pragma unroll
        for (int mt = 0; mt < 4; mt++)
#pragma unroll
            for (int nt = 0; nt < 2; nt++)
                acc[mt][nt] = __builtin_amdgcn_mfma_f32_16x16x32_f16(
                    af[mt], bf[nt], acc[mt][nt], 0, 0, 0);
        __syncthreads();   // all reads done before next staging overwrites
    }
#pragma unroll
    for (int nt = 0; nt < 2; nt++) {
        int col = bn + wc * 32 + nt * 16 + lm;
        float bv = bias[col];
#pragma unroll
        for (int mt = 0; mt < 4; mt++) {
#pragma unroll
            for (int v = 0; v < 4; v++) {
                int row = bm + wr * 64 + mt * 16 + q * 4 + v;
                float val = fmaxf(acc[mt][nt][v] + bv, 0.f);
                if (outh) outh[(size_t)row * N + col] = (_Float16)val;
                else      outf[(size_t)row * N + col] = val;
            }
        }
    }
}

// ---------------- parallel S-fragment build (pi baked into s1f) ----------------
// pi: struct col c = wcb*128 + t*16 + lmc  <->  storage p = wcb*128 + lmc*8 + t.
__global__ __launch_bounds__(256) void build_frags(
    const float* __restrict__ S, _Float16* __restrict__ s1f,
    _Float16* __restrict__ s2f) {
    int i = blockIdx.x * 256 + threadIdx.x;
    if (i < 4 * 16 * 64 * 8) {
        int j = i & 7, lane = (i >> 3) & 63, kk = (i >> 9) & 15, wc = i >> 13;
        int p = kk * 32 + (lane >> 4) * 8 + j;
        int lmc = (p & 127) >> 3, tc = p & 7;
        int c = (p >> 7) * 128 + tc * 16 + lmc;       // pi^-1
        int m = wc * 16 + (lane & 15);
        s1f[i] = (_Float16)S[m * 512 + c];
    } else {
        int i2 = i - 4 * 16 * 64 * 8;
        int j = i2 & 7, lane = (i2 >> 3) & 63, c = (i2 >> 9) & 1,
            tt = (i2 >> 10) & 7, wc = i2 >> 13;
        int kc = c * 32 + (lane >> 4) * 8 + j;
        int n = wc * 128 + tt * 16 + (lane & 15);
        s2f[i2] = (_Float16)S[kc * 512 + n];
    }
}

// ---------------- dense power iteration for tau (single block, S in LDS u8) ----
__global__ __launch_bounds__(512) void power_iter(
    const float* __restrict__ S, float* __restrict__ tau_g) {
    __shared__ unsigned char Sl[64 * 512];   // 0/1, exact
    __shared__ float vv[512], ww[64], red[8];
    __shared__ float nrm_s;
    int t = threadIdx.x;
    int wv = t >> 6, ln = t & 63;
    for (int i = t; i < 64 * 512; i += 512)
        Sl[i] = (unsigned char)(S[i] != 0.f);
    vv[t] = 0.044194173824159216f;  // 1/sqrt(512)
    __syncthreads();

    for (int s = 0; s <= 30; s++) {
        float pr[8];
#pragma unroll
        for (int rr = 0; rr < 8; rr++) {
            int r = wv * 8 + rr;
            float a = 0.f;
#pragma unroll
            for (int e = 0; e < 8; e++)
                a += (float)Sl[r * 512 + e * 64 + ln] * vv[e * 64 + ln];
            pr[rr] = a;
        }
#pragma unroll
        for (int o = 32; o > 0; o >>= 1)
#pragma unroll
            for (int rr = 0; rr < 8; rr++) pr[rr] += __shfl_xor(pr[rr], o, 64);
        if (ln < 8) ww[wv * 8 + ln] = pr[ln];
        __syncthreads();
        float u = vv[t];
#pragma unroll
        for (int j = 0; j < 64; j++) u += (float)Sl[j * 512 + t] * ww[j];
        if (s == 30) {
            float n2 = vv[t] * u;
#pragma unroll
            for (int o = 32; o > 0; o >>= 1) n2 += __shfl_xor(n2, o, 64);
            if (ln == 0) red[wv] = n2;
            __syncthreads();
            if (t == 0) {
                float tot = 0.f;
                for (int qq = 0; qq < 8; qq++) tot += red[qq];
                tau_g[0] = 0.9f / sqrtf(tot);
            }
            return;
        }
        float n2 = u * u;
#pragma unroll
        for (int o = 32; o > 0; o >>= 1) n2 += __shfl_xor(n2, o, 64);
        if (ln == 0) red[wv] = n2;
        __syncthreads();
        if (t == 0) {
            float tot = 0.f;
            for (int qq = 0; qq < 8; qq++) tot += red[qq];
            nrm_s = sqrtf(tot);
        }
        __syncthreads();
        vv[t] = u / nrm_s;
        __syncthreads();
    }
}

// ---------------- Delta-form MFMA PDHG, 8-row tiles, 60 iterations -------------
// Block = 8 batch rows, 4 waves; wave wc owns combos [wc*16,+16) and struct
// cols [wc*128,+128). MFMA tiles are 16-row; rows 8..15 are permanent-zero
// padding (delta planes zero-initialized, lanes q>=2 never publish). Running
// fp32 accumulators a1p (S.xbar) / acc2 (S^T.ylo); LDS carries f16 deltas.
__global__ __launch_bounds__(256, 1) void pdhg_mfma(
    const float* __restrict__ Zb, const float* __restrict__ Xf,
    const _Float16* __restrict__ s1f, const _Float16* __restrict__ s2f,
    const float* __restrict__ tau_p, float* __restrict__ out) {
    __shared__ __align__(16) _Float16 xb_d[16 * XBS];   // delta-xbar, pi-order
    __shared__ __align__(16) _Float16 yl_d[16 * YLS];   // delta-ylo
    __shared__ __align__(16) float red[16][4];
    int tid = threadIdx.x;
    int wc = tid >> 6, l = tid & 63, lm = l & 15, q = l >> 4;
    int b0 = blockIdx.x * 8;
    bool act = (q < 2);            // lanes whose C/D rows are real batch rows

    // constant S fragments -> registers (held across all 60 iterations)
    half8 s1[16], s2[8][2];
#pragma unroll
    for (int kk = 0; kk < 16; kk++)
        s1[kk] = *(const half8*)&s1f[((wc * 16 + kk) * 64 + l) * 8];
#pragma unroll
    for (int t = 0; t < 8; t++)
#pragma unroll
        for (int c = 0; c < 2; c++)
            s2[t][c] = *(const half8*)&s2f[(((wc * 8 + t) * 2 + c) * 64 + l) * 8];

    float z[4][8], x[4][8], xb[4][8], yhi[4][8];
    floatx4 ylo, Bc;
    floatx4 a1p[4] = {{0.f,0.f,0.f,0.f},{0.f,0.f,0.f,0.f},
                      {0.f,0.f,0.f,0.f},{0.f,0.f,0.f,0.f}};   // running S.xbar
    floatx4 acc2[8];                                          // running S^T.ylo
#pragma unroll
    for (int t = 0; t < 8; t++) acc2[t] = floatx4{0.f, 0.f, 0.f, 0.f};
#pragma unroll
    for (int v = 0; v < 4; v++) {
        int row = b0 + ((q * 4 + v) & 7);   // clamped: inactive lanes read valid rows
        Bc[v] = Xf[row * 64 + wc * 16 + lm];
        ylo[v] = 0.f;
#pragma unroll
        for (int t = 0; t < 8; t++) {
            z[v][t] = Zb[(size_t)row * 512 + wc * 128 + t * 16 + lm];
            x[v][t] = 0.f; xb[v][t] = 0.f; yhi[v][t] = 0.f;
        }
    }
    {
        half8 hz = {0, 0, 0, 0, 0, 0, 0, 0};
        for (int i = tid; i < (16 * XBS) / 8; i += 256)
            *(half8*)&xb_d[i * 8] = hz;
        for (int i = tid; i < 16 * YLS; i += 256)
            yl_d[i] = (_Float16)0.f;
    }
    float tau = tau_p[0];
    float sig = tau;
    __syncthreads();

#pragma unroll 1
    for (int it = 0; it < NITERS; ++it) {
        // ---- Kx increment: a1p += d_xbar @ S^T (rows 8..15 read zeros) ----
#pragma unroll
        for (int kk = 0; kk < 16; kk++) {
            half8 ad = *(const half8*)&xb_d[lm * XBS + kk * 32 + q * 8];
            a1p[kk & 3] = __builtin_amdgcn_mfma_f32_16x16x32_f16(ad, s1[kk], a1p[kk & 3], 0, 0, 0);
        }
        floatx4 a1 = (a1p[0] + a1p[1]) + (a1p[2] + a1p[3]);  // = S.xbar_pub
        // ---- y_lo update + publish delta (active rows only) ----
#pragma unroll
        for (int v = 0; v < 4; v++) {
            float yv = fmaxf(ylo[v] + sig * (a1[v] - Bc[v]), 0.f);
            float dy = yv - ylo[v];
            ylo[v] = yv;
            if (act) yl_d[(q * 4 + v) * YLS + wc * 16 + lm] = (_Float16)dy;
        }
        __syncthreads();   // [A] delta-y plane ready
        // ---- KTy increment: acc2 += d_y @ S ----
        half8 a2d[2];
#pragma unroll
        for (int c = 0; c < 2; c++)
            a2d[c] = *(const half8*)&yl_d[lm * YLS + c * 32 + q * 8];
#pragma unroll
        for (int t = 0; t < 8; t++)
#pragma unroll
            for (int c = 0; c < 2; c++)
                acc2[t] = __builtin_amdgcn_mfma_f32_16x16x32_f16(a2d[c], s2[t][c], acc2[t], 0, 0, 0);
        // ---- y_hi update (uses prev xbar), norm partials ----
        float pn[4] = {0.f, 0.f, 0.f, 0.f};
#pragma unroll
        for (int v = 0; v < 4; v++)
#pragma unroll
            for (int t = 0; t < 8; t++) {
                yhi[v][t] = fmaxf(yhi[v][t] - sig * xb[v][t], 0.f);
                float kty = acc2[t][v] - yhi[v][t];
                float d = x[v][t] - tau * kty + tau - z[v][t];
                pn[v] += d * d;
            }
#pragma unroll
        for (int o = 1; o < 16; o <<= 1)
#pragma unroll
            for (int v = 0; v < 4; v++) pn[v] += __shfl_xor(pn[v], o, 64);
        if (lm == 0)
#pragma unroll
            for (int v = 0; v < 4; v++) red[q * 4 + v][wc] = pn[v];
        __syncthreads();   // [B] norm partials ready
        float scale[4];
#pragma unroll
        for (int v = 0; v < 4; v++) {
            floatx4 r = *(const floatx4*)&red[q * 4 + v][0];
            float nrm = sqrtf(r[0] + r[1] + r[2] + r[3]);
            scale[v] = fmaxf(1.f - tau / fmaxf(nrm, 1e-12f), 0.f);
        }
        // ---- prox + delta-xbar publish (pi-order; active rows only) ----
#pragma unroll
        for (int v = 0; v < 4; v++) {
            half8 hd;
#pragma unroll
            for (int t = 0; t < 8; t++) {
                float kty = acc2[t][v] - yhi[v][t];
                float d = x[v][t] - tau * kty + tau - z[v][t];
                float xn = z[v][t] + scale[v] * d;
                float xbn = 2.f * xn - x[v][t];
                hd[t] = (_Float16)(xbn - xb[v][t]);   // delta
                x[v][t] = xn;
                xb[v][t] = xbn;
            }
            if (act)
                *(half8*)&xb_d[(q * 4 + v) * XBS + wc * 128 + lm * 8] = hd;
        }
        __syncthreads();   // [C] delta-xbar plane ready for next iteration
    }
    if (act)
#pragma unroll
        for (int v = 0; v < 4; v++)
#pragma unroll
            for (int t = 0; t < 8; t++)
                out[(size_t)(b0 + q * 4 + v) * 512 + wc * 128 + t * 16 + lm] = x[v][t];
}

// ---------------------------------------------------------------------------
extern "C" void kernel_launch(void* const* d_in, const int* in_sizes, int n_in,
                              void* d_out, int out_size, void* d_ws, size_t ws_size,
                              hipStream_t stream) {
    const float* X  = (const float*)d_in[0];
    const float* W1 = (const float*)d_in[1];
    const float* b1 = (const float*)d_in[2];
    const float* W2 = (const float*)d_in[3];
    const float* b2 = (const float*)d_in[4];
    const float* W3 = (const float*)d_in[5];
    const float* b3 = (const float*)d_in[6];
    const float* S  = (const float*)d_in[7];
    float* out = (float*)d_out;

    char* ws = (char*)d_ws;
    size_t off = 0;
    auto alloc = [&](size_t bytes) {
        void* p = ws + off;
        off += (bytes + 255) & ~(size_t)255;
        return p;
    };
    _Float16* Xh  = (_Float16*)alloc((size_t)BATCH * 64 * 2);
    _Float16* W1t = (_Float16*)alloc((size_t)64 * 1024 * 2);
    _Float16* W2t = (_Float16*)alloc((size_t)1024 * 1024 * 2);
    _Float16* W3t = (_Float16*)alloc((size_t)1024 * 512 * 2);
    _Float16* H1  = (_Float16*)alloc((size_t)BATCH * 1024 * 2);
    _Float16* H2  = (_Float16*)alloc((size_t)BATCH * 1024 * 2);
    float*    Zb  = (float*)alloc((size_t)BATCH * 512 * 4);
    _Float16* s1f = (_Float16*)alloc((size_t)4 * 16 * 64 * 8 * 2);
    _Float16* s2f = (_Float16*)alloc((size_t)4 * 8 * 2 * 64 * 8 * 2);
    float*    tau = (float*)alloc(256);

    hipLaunchKernelGGL(cast_x, dim3(512), dim3(256), 0, stream, X, Xh, BATCH * 64);
    hipLaunchKernelGGL(tcast, dim3(32, 2),  dim3(32, 8), 0, stream, W1, W1t, 64, 1024);
    hipLaunchKernelGGL(tcast, dim3(32, 32), dim3(32, 8), 0, stream, W2, W2t, 1024, 1024);
    hipLaunchKernelGGL(tcast, dim3(16, 32), dim3(32, 8), 0, stream, W3, W3t, 1024, 512);
    hipLaunchKernelGGL(build_frags, dim3((4*16*64*8 + 4*8*2*64*8) / 256), dim3(256), 0,
                       stream, S, s1f, s2f);
    hipLaunchKernelGGL(power_iter, dim3(1), dim3(512), 0, stream, S, tau);
    hipLaunchKernelGGL(gemm_relu, dim3(16, 16), dim3(256), 0, stream,
                       Xh, W1t, b1, H1, (float*)nullptr, 1024, 64);
    hipLaunchKernelGGL(gemm_relu, dim3(16, 16), dim3(256), 0, stream,
                       H1, W2t, b2, H2, (float*)nullptr, 1024, 1024);
    hipLaunchKernelGGL(gemm_relu, dim3(8, 16), dim3(256), 0, stream,
                       H2, W3t, b3, (_Float16*)nullptr, Zb, 512, 1024);
    hipLaunchKernelGGL(pdhg_mfma, dim3(BATCH / 8), dim3(256), 0, stream,
                       Zb, X, s1f, s2f, tau, out);
}

// Round 8
// 349.589 us; speedup vs baseline: 6.6904x; 1.0284x over previous
//
#include <hip/hip_runtime.h>

// ---------------------------------------------------------------------------
// MatchNet: 3-layer MLP (relu after every layer) -> batched PDHG LP solve.
// Shapes: X[2048,64], W1[64,1024], W2[1024,1024], W3[1024,512], S[64,512].
// Output: x [2048,512] fp32.
//
// R8 (= R7 with the cvt_pkrtz type fix): (a) pdhg element-wise core in
// packed-fp32 (floatx2 -> v_pk_fma/add/max) over the MFMA C/D .xy/.zw pairs;
// d stashed; v_cvt_pkrtz_f16_f32 (returns __fp16x2!) for delta planes.
// (b) 5 prep kernels merged into one. (c) power_iter via per-thread bitmasks.
// ---------------------------------------------------------------------------

typedef _Float16 half8 __attribute__((ext_vector_type(8)));
typedef __fp16 fp16x2 __attribute__((ext_vector_type(2)));
typedef __fp16 fp16x4 __attribute__((ext_vector_type(4)));
typedef __fp16 fp16x8 __attribute__((ext_vector_type(8)));
typedef float floatx4 __attribute__((ext_vector_type(4)));
typedef float floatx2 __attribute__((ext_vector_type(2)));

#define BATCH 2048
#define NITERS 60
#define XBS 520   // delta-xbar LDS row stride in halves (16B-aligned rows)
#define YLS 72    // delta-ylo  LDS row stride in halves

typedef const __attribute__((address_space(1))) unsigned int* gptr_as1;
typedef __attribute__((address_space(3))) unsigned int* lptr_as3;
__device__ __forceinline__ void gl_lds16(const _Float16* g, _Float16* s) {
    __builtin_amdgcn_global_load_lds((gptr_as1)g, (lptr_as3)s, 16, 0, 0);
}
__device__ __forceinline__ floatx2 pmax0(floatx2 a) {
    return __builtin_elementwise_max(a, floatx2{0.f, 0.f});
}

// ---------------- merged prep: cast X, transpose-cast W1/W2/W3, S frags --------
// blocks [0,512): Xh = f16(X). [512,576): W1t. [576,1600): W2t. [1600,2112):
// W3t. [2112,2368): s1f/s2f MFMA fragments of S (pi baked into s1f).
__global__ __launch_bounds__(256) void prep(
    const float* __restrict__ X, _Float16* __restrict__ Xh,
    const float* __restrict__ W1, _Float16* __restrict__ W1t,
    const float* __restrict__ W2, _Float16* __restrict__ W2t,
    const float* __restrict__ W3, _Float16* __restrict__ W3t,
    const float* __restrict__ S, _Float16* __restrict__ s1f,
    _Float16* __restrict__ s2f) {
    __shared__ float tile[32][33];
    int tid = threadIdx.x;
    int bid = blockIdx.x;
    if (bid < 512) {
        int i = bid * 256 + tid;
        Xh[i] = (_Float16)X[i];
        return;
    }
    bid -= 512;
    if (bid < 1600) {   // transpose+cast W[K][N] -> Wt[N][K]
        const float* W; _Float16* Wt; int K, N, b;
        if (bid < 64)        { W = W1; Wt = W1t; K = 64;   N = 1024; b = bid; }
        else if (bid < 1088) { W = W2; Wt = W2t; K = 1024; N = 1024; b = bid - 64; }
        else                 { W = W3; Wt = W3t; K = 1024; N = 512;  b = bid - 1088; }
        int nbx = N / 32;
        int n0 = (b % nbx) * 32, k0 = (b / nbx) * 32;
        int tx = tid & 31, ty = tid >> 5;
#pragma unroll
        for (int i = 0; i < 4; i++)
            tile[ty + i * 8][tx] = W[(size_t)(k0 + ty + i * 8) * N + n0 + tx];
        __syncthreads();
#pragma unroll
        for (int i = 0; i < 4; i++)
            Wt[(size_t)(n0 + ty + i * 8) * K + k0 + tx] = (_Float16)tile[tx][ty + i * 8];
        return;
    }
    bid -= 1600;
    int i = bid * 256 + tid;       // 0 .. 65535
    if (i < 4 * 16 * 64 * 8) {     // s1f: B-frag of S^T, k-axis in pi-order
        int j = i & 7, lane = (i >> 3) & 63, kk = (i >> 9) & 15, wc = i >> 13;
        int p = kk * 32 + (lane >> 4) * 8 + j;
        int lmc = (p & 127) >> 3, tc = p & 7;
        int c = (p >> 7) * 128 + tc * 16 + lmc;       // pi^-1
        int m = wc * 16 + (lane & 15);
        s1f[i] = (_Float16)S[m * 512 + c];
    } else {                       // s2f: B-frag of S (k = combos)
        int i2 = i - 4 * 16 * 64 * 8;
        int j = i2 & 7, lane = (i2 >> 3) & 63, c = (i2 >> 9) & 1,
            tt = (i2 >> 10) & 7, wc = i2 >> 13;
        int kc = c * 32 + (lane >> 4) * 8 + j;
        int n = wc * 128 + tt * 16 + (lane & 15);
        s2f[i2] = (_Float16)S[kc * 512 + n];
    }
}

// ---------------- GEMM: out = relu(A[M,K] @ W[K,N] + bias), f16 in, fp32 acc ---
__global__ __launch_bounds__(256) void gemm_relu(
    const _Float16* __restrict__ A, const _Float16* __restrict__ Wt,
    const float* __restrict__ bias, _Float16* __restrict__ outh,
    float* __restrict__ outf, int N, int K) {
    __shared__ __align__(16) _Float16 As[128 * 32];
    __shared__ __align__(16) _Float16 Bs[64 * 32];
    int tid = threadIdx.x;
    int bm = blockIdx.y * 128;
    int bn = blockIdx.x * 64;
    int w = tid >> 6, l = tid & 63;
    int wr = w >> 1, wc = w & 1;
    int lm = l & 15, q = l >> 4;
    floatx4 acc[4][2] = {};

    int sr = l >> 2;
    int sc = (l & 3) * 8;
    const _Float16* ag0 = A + (size_t)(bm + w * 32 + sr) * K + sc;
    const _Float16* ag1 = A + (size_t)(bm + w * 32 + 16 + sr) * K + sc;
    _Float16* as0 = &As[(w * 32) * 32];
    _Float16* as1 = &As[(w * 32 + 16) * 32];
    const _Float16* bg = Wt + (size_t)(bn + w * 16 + sr) * K + sc;
    _Float16* bs = &Bs[(w * 16) * 32];

    for (int k0 = 0; k0 < K; k0 += 32) {
        gl_lds16(ag0 + k0, as0);
        gl_lds16(ag1 + k0, as1);
        gl_lds16(bg + k0, bs);
        __syncthreads();
        half8 af[4], bf[2];
#pragma unroll
        for (int mt = 0; mt < 4; mt++)
            af[mt] = *(const half8*)&As[(wr * 64 + mt * 16 + lm) * 32 + q * 8];
#pragma unroll
        for (int nt = 0; nt < 2; nt++)
            bf[nt] = *(const half8*)&Bs[(wc * 32 + nt * 16 + lm) * 32 + q * 8];
#pragma unroll
        for (int mt = 0; mt < 4; mt++)
#pragma unroll
            for (int nt = 0; nt < 2; nt++)
                acc[mt][nt] = __builtin_amdgcn_mfma_f32_16x16x32_f16(
                    af[mt], bf[nt], acc[mt][nt], 0, 0, 0);
        __syncthreads();
    }
#pragma unroll
    for (int nt = 0; nt < 2; nt++) {
        int col = bn + wc * 32 + nt * 16 + lm;
        float bv = bias[col];
#pragma unroll
        for (int mt = 0; mt < 4; mt++) {
#pragma unroll
            for (int v = 0; v < 4; v++) {
                int row = bm + wr * 64 + mt * 16 + q * 4 + v;
                float val = fmaxf(acc[mt][nt][v] + bv, 0.f);
                if (outh) outh[(size_t)row * N + col] = (_Float16)val;
                else      outf[(size_t)row * N + col] = val;
            }
        }
    }
}

// ---------------- power iteration for tau: S as per-thread bitmasks ------------
__global__ __launch_bounds__(512) void power_iter(
    const float* __restrict__ S, float* __restrict__ tau_g) {
    __shared__ float vv[512], ww[64], red[8];
    int t = threadIdx.x, wv = t >> 6, ln = t & 63;
    // row bits: bit (rr*8+e) = S[wv*8+rr][e*64+ln] != 0
    unsigned long long rm = 0;
    for (int rr = 0; rr < 8; rr++)
        for (int e = 0; e < 8; e++)
            if (S[(wv * 8 + rr) * 512 + e * 64 + ln] != 0.f)
                rm |= 1ull << (rr * 8 + e);
    // col bits: bit j = S[j][t] != 0
    unsigned long long cm = 0;
    for (int j = 0; j < 64; j++)
        if (S[j * 512 + t] != 0.f) cm |= 1ull << j;
    vv[t] = 0.044194173824159216f;  // 1/sqrt(512)
    __syncthreads();
    for (int s = 0; s <= 30; s++) {
        float ve[8];
#pragma unroll
        for (int e = 0; e < 8; e++) ve[e] = vv[e * 64 + ln];
        float pr[8];
#pragma unroll
        for (int rr = 0; rr < 8; rr++) {
            unsigned int bits = (unsigned int)(rm >> (rr * 8)) & 0xffu;
            float a = 0.f;
#pragma unroll
            for (int e = 0; e < 8; e++) a += (bits >> e & 1) ? ve[e] : 0.f;
            pr[rr] = a;
        }
#pragma unroll
        for (int o = 32; o > 0; o >>= 1)
#pragma unroll
            for (int rr = 0; rr < 8; rr++) pr[rr] += __shfl_xor(pr[rr], o, 64);
        if (ln < 8) ww[wv * 8 + ln] = pr[ln];
        __syncthreads();
        float u = vv[t];
#pragma unroll
        for (int j = 0; j < 64; j++) u += (cm >> j & 1) ? ww[j] : 0.f;
        float n2 = (s == 30) ? vv[t] * u : u * u;
#pragma unroll
        for (int o = 32; o > 0; o >>= 1) n2 += __shfl_xor(n2, o, 64);
        if (ln == 0) red[wv] = n2;
        __syncthreads();
        float tot = ((red[0] + red[1]) + (red[2] + red[3])) +
                    ((red[4] + red[5]) + (red[6] + red[7]));
        if (s == 30) {
            if (t == 0) tau_g[0] = 0.9f / sqrtf(tot);
            return;
        }
        float nv = u / sqrtf(tot);
        __syncthreads();   // red reads done before next step's red write
        vv[t] = nv;
        __syncthreads();   // vv visible for next step
    }
}

// ---------------- Delta-form MFMA PDHG, packed-fp32 core, 60 iterations --------
// Block = 8 batch rows, 4 waves; wave wc owns combos [wc*16,+16) and struct
// cols [wc*128,+128). State paired over C/D register components (v=2vp+c):
// floatx2 ops -> v_pk_fma/add/max. Delta planes packed via v_cvt_pkrtz.
__global__ __launch_bounds__(256, 1) void pdhg_mfma(
    const float* __restrict__ Zb, const float* __restrict__ Xf,
    const _Float16* __restrict__ s1f, const _Float16* __restrict__ s2f,
    const float* __restrict__ tau_p, float* __restrict__ out) {
    __shared__ __align__(16) _Float16 xb_d[16 * XBS];
    __shared__ __align__(16) _Float16 yl_d[16 * YLS];
    __shared__ __align__(16) float red[16][4];
    int tid = threadIdx.x;
    int wc = tid >> 6, l = tid & 63, lm = l & 15, q = l >> 4;
    int b0 = blockIdx.x * 8;
    bool act = (q < 2);

    half8 s1[16], s2[8][2];
#pragma unroll
    for (int kk = 0; kk < 16; kk++)
        s1[kk] = *(const half8*)&s1f[((wc * 16 + kk) * 64 + l) * 8];
#pragma unroll
    for (int t = 0; t < 8; t++)
#pragma unroll
        for (int c = 0; c < 2; c++)
            s2[t][c] = *(const half8*)&s2f[(((wc * 8 + t) * 2 + c) * 64 + l) * 8];

    // paired state: [vp][t], components are rows v = 2vp, 2vp+1
    floatx2 z2[2][8], tz2[2][8], x2[2][8], xb2[2][8], yh2[2][8], d2[2][8];
    floatx2 ylo2[2], Bc2[2];
    floatx4 a1p[4] = {};
    floatx4 acc2[8] = {};
    float tau = tau_p[0];
    float sig = tau;
#pragma unroll
    for (int vp = 0; vp < 2; vp++) {
        int r0 = b0 + ((q * 4 + 2 * vp) & 7);
        int r1 = b0 + ((q * 4 + 2 * vp + 1) & 7);
        Bc2[vp] = floatx2{Xf[r0 * 64 + wc * 16 + lm], Xf[r1 * 64 + wc * 16 + lm]};
        ylo2[vp] = floatx2{0.f, 0.f};
#pragma unroll
        for (int t = 0; t < 8; t++) {
            int cc = wc * 128 + t * 16 + lm;
            z2[vp][t] = floatx2{Zb[(size_t)r0 * 512 + cc], Zb[(size_t)r1 * 512 + cc]};
            tz2[vp][t] = tau - z2[vp][t];
            x2[vp][t] = floatx2{0.f, 0.f};
            xb2[vp][t] = floatx2{0.f, 0.f};
            yh2[vp][t] = floatx2{0.f, 0.f};
        }
    }
    {
        half8 hz = {0, 0, 0, 0, 0, 0, 0, 0};
        for (int i = tid; i < (16 * XBS) / 8; i += 256)
            *(half8*)&xb_d[i * 8] = hz;
        for (int i = tid; i < 16 * YLS; i += 256)
            yl_d[i] = (_Float16)0.f;
    }
    __syncthreads();

#pragma unroll 1
    for (int it = 0; it < NITERS; ++it) {
        // ---- Kx increment: a1p += d_xbar @ S^T ----
#pragma unroll
        for (int kk = 0; kk < 16; kk++) {
            half8 ad = *(const half8*)&xb_d[lm * XBS + kk * 32 + q * 8];
            a1p[kk & 3] = __builtin_amdgcn_mfma_f32_16x16x32_f16(ad, s1[kk], a1p[kk & 3], 0, 0, 0);
        }
        floatx4 a1 = (a1p[0] + a1p[1]) + (a1p[2] + a1p[3]);
        // ---- y_lo update + publish delta (packed) ----
#pragma unroll
        for (int vp = 0; vp < 2; vp++) {
            floatx2 av = (vp == 0) ? floatx2{a1.x, a1.y} : floatx2{a1.z, a1.w};
            floatx2 yv = pmax0(ylo2[vp] + sig * (av - Bc2[vp]));
            floatx2 dy = yv - ylo2[vp];
            ylo2[vp] = yv;
            if (act) {
                fp16x2 p = __builtin_amdgcn_cvt_pkrtz(dy.x, dy.y);
                int a0 = (q * 4 + 2 * vp) * YLS + wc * 16 + lm;
                yl_d[a0] = p[0];
                yl_d[a0 + YLS] = p[1];
            }
        }
        __syncthreads();   // [A]
        // ---- KTy increment: acc2 += d_y @ S ----
        half8 a2d[2];
#pragma unroll
        for (int c = 0; c < 2; c++)
            a2d[c] = *(const half8*)&yl_d[lm * YLS + c * 32 + q * 8];
#pragma unroll
        for (int t = 0; t < 8; t++)
#pragma unroll
            for (int c = 0; c < 2; c++)
                acc2[t] = __builtin_amdgcn_mfma_f32_16x16x32_f16(a2d[c], s2[t][c], acc2[t], 0, 0, 0);
        // ---- packed: y_hi update, d = x - tau*kty + (tau - z), norm partials ----
        floatx2 pn2[2] = {floatx2{0.f, 0.f}, floatx2{0.f, 0.f}};
#pragma unroll
        for (int vp = 0; vp < 2; vp++)
#pragma unroll
            for (int t = 0; t < 8; t++) {
                floatx2 accp = (vp == 0) ? floatx2{acc2[t].x, acc2[t].y}
                                         : floatx2{acc2[t].z, acc2[t].w};
                yh2[vp][t] = pmax0(yh2[vp][t] - sig * xb2[vp][t]);
                floatx2 kty = accp - yh2[vp][t];
                floatx2 dd = (x2[vp][t] - tau * kty) + tz2[vp][t];
                d2[vp][t] = dd;
                pn2[vp] += dd * dd;
            }
        float pn[4] = {pn2[0].x, pn2[0].y, pn2[1].x, pn2[1].y};
#pragma unroll
        for (int o = 1; o < 16; o <<= 1)
#pragma unroll
            for (int v = 0; v < 4; v++) pn[v] += __shfl_xor(pn[v], o, 64);
        if (lm == 0)
#pragma unroll
            for (int v = 0; v < 4; v++) red[q * 4 + v][wc] = pn[v];
        __syncthreads();   // [B]
        floatx2 sc2[2];
#pragma unroll
        for (int vp = 0; vp < 2; vp++)
#pragma unroll
            for (int c = 0; c < 2; c++) {
                int v = 2 * vp + c;
                floatx4 r = *(const floatx4*)&red[q * 4 + v][0];
                float nrm = sqrtf((r.x + r.y) + (r.z + r.w));
                float s = fmaxf(1.f - tau / fmaxf(nrm, 1e-12f), 0.f);
                if (c == 0) sc2[vp].x = s; else sc2[vp].y = s;
            }
        // ---- packed prox + delta-xbar publish ----
#pragma unroll
        for (int vp = 0; vp < 2; vp++) {
#pragma unroll
            for (int t = 0; t < 8; t++) {
                floatx2 xn = z2[vp][t] + sc2[vp] * d2[vp][t];
                floatx2 xbn = 2.f * xn - x2[vp][t];
                d2[vp][t] = xbn - xb2[vp][t];   // reuse d2 as delta
                x2[vp][t] = xn;
                xb2[vp][t] = xbn;
            }
            if (act) {
#pragma unroll
                for (int c = 0; c < 2; c++) {
                    fp16x2 p0 = __builtin_amdgcn_cvt_pkrtz(
                        (c == 0) ? d2[vp][0].x : d2[vp][0].y,
                        (c == 0) ? d2[vp][1].x : d2[vp][1].y);
                    fp16x2 p1 = __builtin_amdgcn_cvt_pkrtz(
                        (c == 0) ? d2[vp][2].x : d2[vp][2].y,
                        (c == 0) ? d2[vp][3].x : d2[vp][3].y);
                    fp16x2 p2 = __builtin_amdgcn_cvt_pkrtz(
                        (c == 0) ? d2[vp][4].x : d2[vp][4].y,
                        (c == 0) ? d2[vp][5].x : d2[vp][5].y);
                    fp16x2 p3 = __builtin_amdgcn_cvt_pkrtz(
                        (c == 0) ? d2[vp][6].x : d2[vp][6].y,
                        (c == 0) ? d2[vp][7].x : d2[vp][7].y);
                    fp16x4 q0 = __builtin_shufflevector(p0, p1, 0, 1, 2, 3);
                    fp16x4 q1 = __builtin_shufflevector(p2, p3, 0, 1, 2, 3);
                    fp16x8 hd = __builtin_shufflevector(q0, q1, 0, 1, 2, 3, 4, 5, 6, 7);
                    int v = 2 * vp + c;
                    *(fp16x8*)&xb_d[(q * 4 + v) * XBS + wc * 128 + lm * 8] = hd;
                }
            }
        }
        __syncthreads();   // [C]
    }
    if (act)
#pragma unroll
        for (int vp = 0; vp < 2; vp++)
#pragma unroll
            for (int t = 0; t < 8; t++) {
                int cc = wc * 128 + t * 16 + lm;
                out[(size_t)(b0 + q * 4 + 2 * vp) * 512 + cc] = x2[vp][t].x;
                out[(size_t)(b0 + q * 4 + 2 * vp + 1) * 512 + cc] = x2[vp][t].y;
            }
}

// ---------------------------------------------------------------------------
extern "C" void kernel_launch(void* const* d_in, const int* in_sizes, int n_in,
                              void* d_out, int out_size, void* d_ws, size_t ws_size,
                              hipStream_t stream) {
    const float* X  = (const float*)d_in[0];
    const float* W1 = (const float*)d_in[1];
    const float* b1 = (const float*)d_in[2];
    const float* W2 = (const float*)d_in[3];
    const float* b2 = (const float*)d_in[4];
    const float* W3 = (const float*)d_in[5];
    const float* b3 = (const float*)d_in[6];
    const float* S  = (const float*)d_in[7];
    float* out = (float*)d_out;

    char* ws = (char*)d_ws;
    size_t off = 0;
    auto alloc = [&](size_t bytes) {
        void* p = ws + off;
        off += (bytes + 255) & ~(size_t)255;
        return p;
    };
    _Float16* Xh  = (_Float16*)alloc((size_t)BATCH * 64 * 2);
    _Float16* W1t = (_Float16*)alloc((size_t)64 * 1024 * 2);
    _Float16* W2t = (_Float16*)alloc((size_t)1024 * 1024 * 2);
    _Float16* W3t = (_Float16*)alloc((size_t)1024 * 512 * 2);
    _Float16* H1  = (_Float16*)alloc((size_t)BATCH * 1024 * 2);
    _Float16* H2  = (_Float16*)alloc((size_t)BATCH * 1024 * 2);
    float*    Zb  = (float*)alloc((size_t)BATCH * 512 * 4);
    _Float16* s1f = (_Float16*)alloc((size_t)4 * 16 * 64 * 8 * 2);
    _Float16* s2f = (_Float16*)alloc((size_t)4 * 8 * 2 * 64 * 8 * 2);
    float*    tau = (float*)alloc(256);

    hipLaunchKernelGGL(prep, dim3(2368), dim3(256), 0, stream,
                       X, Xh, W1, W1t, W2, W2t, W3, W3t, S, s1f, s2f);
    hipLaunchKernelGGL(power_iter, dim3(1), dim3(512), 0, stream, S, tau);
    hipLaunchKernelGGL(gemm_relu, dim3(16, 16), dim3(256), 0, stream,
                       Xh, W1t, b1, H1, (float*)nullptr, 1024, 64);
    hipLaunchKernelGGL(gemm_relu, dim3(16, 16), dim3(256), 0, stream,
                       H1, W2t, b2, H2, (float*)nullptr, 1024, 1024);
    hipLaunchKernelGGL(gemm_relu, dim3(8, 16), dim3(256), 0, stream,
                       H2, W3t, b3, (_Float16*)nullptr, Zb, 512, 1024);
    hipLaunchKernelGGL(pdhg_mfma, dim3(BATCH / 8), dim3(256), 0, stream,
                       Zb, X, s1f, s2f, tau, out);
}